// Round 1
// baseline (12464.059 us; speedup 1.0000x reference)
//
#include <hip/hip_runtime.h>
#include <hip/hip_bf16.h>
#include <math.h>

// ---------------------------------------------------------------------------
// Problem constants
// ---------------------------------------------------------------------------
#define BB 32
#define SS 60
#define NN_ 25
#define DIN 100
#define BN 800           // B*N
#define GRU_H 512
#define FDIM 1024        // TEMB+SEMB
#define CH 256
#define OUTD 512

// workspace float offsets
static const size_t O_HSEQ = 0;                     // 48000*512 = 24,576,000
static const size_t O_HBUF = 24576000;              // [par][dir][800*512] = 1,638,400
static const size_t O_HN   = 26214400;              // 800*1024
static const size_t O_QKV  = 27033600;              // 800*2048
static const size_t O_SC   = 28672000;              // 256*640
static const size_t O_ADJ  = 28835840;              // 640
static const size_t O_WR   = 28836480;              // 800*512
static const size_t O_TEP  = 29246080;              // 25*512
static const size_t O_TE   = 29258880;              // 25*512
static const size_t O_XCAT = 29271680;              // 800*1280
static const size_t O_GTMP = 30295680;              // 800*256
static const size_t O_XG0  = 30500480;              // 800*256
static const size_t O_XG1  = 30705280;              // 800*256
static const size_t O_XG2  = 30910080;              // 800*256

// ---------------------------------------------------------------------------
// helpers
// ---------------------------------------------------------------------------
__device__ __forceinline__ void block_reduce2(float& s, float& q, float* scratch)
{
  __syncthreads();
  #pragma unroll
  for (int off = 32; off > 0; off >>= 1) {
    s += __shfl_down(s, off);
    q += __shfl_down(q, off);
  }
  int tid = threadIdx.x;
  int w = tid >> 6;
  if ((tid & 63) == 0) { scratch[w * 2] = s; scratch[w * 2 + 1] = q; }
  __syncthreads();
  if (tid == 0) {
    float ss = 0.f, qq = 0.f;
    int nw = blockDim.x >> 6;
    for (int i = 0; i < nw; i++) { ss += scratch[i * 2]; qq += scratch[i * 2 + 1]; }
    scratch[0] = ss; scratch[1] = qq;
  }
  __syncthreads();
  s = scratch[0]; q = scratch[1];
}

// ---------------------------------------------------------------------------
// K1: fused input MLP (100->256 relu ->512 relu) + LayerNorm(512)
// grid: 48000/4 blocks, 256 threads. Writes hseq[(bn*60+s)*512 + c]
// ---------------------------------------------------------------------------
__global__ __launch_bounds__(256) void k_mlp(
    const float* __restrict__ x,
    const float* __restrict__ w1, const float* __restrict__ b1,
    const float* __restrict__ w2, const float* __restrict__ b2,
    const float* __restrict__ g, const float* __restrict__ be,
    float* __restrict__ hseq)
{
  const int R = 4;
  __shared__ float xs[R][DIN];
  __shared__ float h1s[R][256];
  __shared__ float h2s[R][512];
  __shared__ float scratch[8];
  int tid = threadIdx.x;
  int r0 = blockIdx.x * R;

  for (int idx = tid; idx < R * DIN; idx += 256) {
    int rr = idx / DIN, d = idx % DIN;
    int r = r0 + rr;
    int bn = r / SS, s = r % SS;
    int b = bn / NN_, n = bn % NN_;
    xs[rr][d] = x[(((size_t)b * SS + s) * NN_ + n) * DIN + d];
  }
  __syncthreads();
  {
    float acc[R];
    float bv = b1[tid];
    #pragma unroll
    for (int rr = 0; rr < R; rr++) acc[rr] = bv;
    for (int d = 0; d < DIN; d++) {
      float wv = w1[d * 256 + tid];
      #pragma unroll
      for (int rr = 0; rr < R; rr++) acc[rr] += xs[rr][d] * wv;
    }
    #pragma unroll
    for (int rr = 0; rr < R; rr++) h1s[rr][tid] = fmaxf(acc[rr], 0.f);
  }
  __syncthreads();
  {
    float acc0[R], acc1[R];
    float bv0 = b2[tid], bv1 = b2[tid + 256];
    #pragma unroll
    for (int rr = 0; rr < R; rr++) { acc0[rr] = bv0; acc1[rr] = bv1; }
    for (int d = 0; d < 256; d++) {
      float w0 = w2[d * 512 + tid];
      float w1v = w2[d * 512 + tid + 256];
      #pragma unroll
      for (int rr = 0; rr < R; rr++) {
        float h = h1s[rr][d];
        acc0[rr] += h * w0;
        acc1[rr] += h * w1v;
      }
    }
    #pragma unroll
    for (int rr = 0; rr < R; rr++) {
      h2s[rr][tid] = fmaxf(acc0[rr], 0.f);
      h2s[rr][tid + 256] = fmaxf(acc1[rr], 0.f);
    }
  }
  __syncthreads();
  for (int rr = 0; rr < R; rr++) {
    float v0 = h2s[rr][tid], v1 = h2s[rr][tid + 256];
    float s = v0 + v1, q = v0 * v0 + v1 * v1;
    block_reduce2(s, q, scratch);
    float mean = s * (1.f / 512.f);
    float var = q * (1.f / 512.f) - mean * mean;
    float rs = rsqrtf(var + 1e-5f);
    size_t r = (size_t)(r0 + rr);
    hseq[r * 512 + tid] = (v0 - mean) * rs * g[tid] + be[tid];
    hseq[r * 512 + tid + 256] = (v1 - mean) * rs * g[tid + 256] + be[tid + 256];
  }
}

// ---------------------------------------------------------------------------
// K2: one GRU step, both directions (blockIdx.z). Fused gates + hidden update.
// grid: (512/32, ceil(800/64), 2), 256 threads.
// ---------------------------------------------------------------------------
__global__ __launch_bounds__(256) void k_gru_step(
    const float* __restrict__ hseq,
    const float* __restrict__ wih_f, const float* __restrict__ whh_f,
    const float* __restrict__ bih_f, const float* __restrict__ bhh_f,
    const float* __restrict__ wih_b, const float* __restrict__ whh_b,
    const float* __restrict__ bih_b, const float* __restrict__ bhh_b,
    float* __restrict__ hbuf, int t)
{
  __shared__ float Xs[16][68];
  __shared__ float Hs[16][68];
  __shared__ float Wt[6][16][34];

  const int dir = blockIdx.z;
  const float* __restrict__ wih = dir ? wih_b : wih_f;
  const float* __restrict__ whh = dir ? whh_b : whh_f;
  const float* __restrict__ bih = dir ? bih_b : bih_f;
  const float* __restrict__ bhh = dir ? bhh_b : bhh_f;
  const int xt = dir ? (SS - 1 - t) : t;
  const float* __restrict__ hprev = hbuf + (size_t)(t & 1) * 819200 + (size_t)dir * 409600;
  float* __restrict__ hnew = hbuf + (size_t)((t + 1) & 1) * 819200 + (size_t)dir * 409600;

  const int tid = threadIdx.x;
  const int tx = tid & 15, ty = tid >> 4;
  const int j0g = blockIdx.x * 32;
  const int m0g = blockIdx.y * 64;

  float accr[4][2] = {{0.f}}, accz[4][2] = {{0.f}}, accin[4][2] = {{0.f}}, acchn[4][2] = {{0.f}};

  const int lm = tid >> 2;
  const int lkq = (tid & 3) * 4;
  const int lmg = m0g + lm;

  for (int k0 = 0; k0 < 512; k0 += 16) {
    float xv[4] = {0.f, 0.f, 0.f, 0.f}, hv[4] = {0.f, 0.f, 0.f, 0.f};
    if (lmg < BN) {
      float4 a4 = *reinterpret_cast<const float4*>(hseq + ((size_t)lmg * SS + xt) * 512 + k0 + lkq);
      xv[0] = a4.x; xv[1] = a4.y; xv[2] = a4.z; xv[3] = a4.w;
      float4 h4 = *reinterpret_cast<const float4*>(hprev + (size_t)lmg * 512 + k0 + lkq);
      hv[0] = h4.x; hv[1] = h4.y; hv[2] = h4.z; hv[3] = h4.w;
    }
    #pragma unroll
    for (int i = 0; i < 4; i++) { Xs[lkq + i][lm] = xv[i]; Hs[lkq + i][lm] = hv[i]; }

    #pragma unroll
    for (int q3 = 0; q3 < 3; q3++) {
      int s = tid + q3 * 256;
      int tile = s >> 7;
      int rr = s & 127;
      int jj = rr >> 2;
      int kq = (rr & 3) * 4;
      const float* src = (tile < 3) ? wih : whh;
      int gate = (tile < 3) ? tile : (tile - 3);
      int jglob = gate * 512 + j0g + jj;
      float4 w4 = *reinterpret_cast<const float4*>(src + (size_t)jglob * 512 + k0 + kq);
      Wt[tile][kq + 0][jj] = w4.x; Wt[tile][kq + 1][jj] = w4.y;
      Wt[tile][kq + 2][jj] = w4.z; Wt[tile][kq + 3][jj] = w4.w;
    }
    __syncthreads();

    #pragma unroll
    for (int k = 0; k < 16; k++) {
      float4 a4 = *reinterpret_cast<const float4*>(&Xs[k][ty * 4]);
      float4 h4 = *reinterpret_cast<const float4*>(&Hs[k][ty * 4]);
      float xr[4] = {a4.x, a4.y, a4.z, a4.w};
      float hr[4] = {h4.x, h4.y, h4.z, h4.w};
      float2 wr2 = *reinterpret_cast<const float2*>(&Wt[0][k][tx * 2]);
      float2 wz2 = *reinterpret_cast<const float2*>(&Wt[1][k][tx * 2]);
      float2 wn2 = *reinterpret_cast<const float2*>(&Wt[2][k][tx * 2]);
      float2 vr2 = *reinterpret_cast<const float2*>(&Wt[3][k][tx * 2]);
      float2 vz2 = *reinterpret_cast<const float2*>(&Wt[4][k][tx * 2]);
      float2 vn2 = *reinterpret_cast<const float2*>(&Wt[5][k][tx * 2]);
      float wr[2] = {wr2.x, wr2.y}, wz[2] = {wz2.x, wz2.y}, wn[2] = {wn2.x, wn2.y};
      float vr[2] = {vr2.x, vr2.y}, vz[2] = {vz2.x, vz2.y}, vn[2] = {vn2.x, vn2.y};
      #pragma unroll
      for (int i = 0; i < 4; i++) {
        #pragma unroll
        for (int jj = 0; jj < 2; jj++) {
          accr[i][jj]  += xr[i] * wr[jj] + hr[i] * vr[jj];
          accz[i][jj]  += xr[i] * wz[jj] + hr[i] * vz[jj];
          accin[i][jj] += xr[i] * wn[jj];
          acchn[i][jj] += hr[i] * vn[jj];
        }
      }
    }
    __syncthreads();
  }

  #pragma unroll
  for (int i = 0; i < 4; i++) {
    int mg = m0g + ty * 4 + i;
    if (mg >= BN) continue;
    #pragma unroll
    for (int jj = 0; jj < 2; jj++) {
      int j = j0g + tx * 2 + jj;
      float rr = accr[i][jj] + bih[j] + bhh[j];
      float zz = accz[i][jj] + bih[512 + j] + bhh[512 + j];
      float r = 1.f / (1.f + expf(-rr));
      float z = 1.f / (1.f + expf(-zz));
      float n = tanhf(accin[i][jj] + bih[1024 + j] + r * (acchn[i][jj] + bhh[1024 + j]));
      float hp = hprev[(size_t)mg * 512 + j];
      hnew[(size_t)mg * 512 + j] = (1.f - z) * n + z * hp;
    }
  }
}

// ---------------------------------------------------------------------------
// K3: hn = LN(concat(hf, hb)) over 1024. grid 800, 256 threads.
// ---------------------------------------------------------------------------
__global__ __launch_bounds__(256) void k_ln_hn(
    const float* __restrict__ hf, const float* __restrict__ hb,
    const float* __restrict__ g, const float* __restrict__ be,
    float* __restrict__ hn)
{
  __shared__ float scratch[8];
  int row = blockIdx.x, tid = threadIdx.x;
  float v[4];
  float s = 0.f, q = 0.f;
  #pragma unroll
  for (int p = 0; p < 4; p++) {
    int c = p * 256 + tid;
    float val = (c < 512) ? hf[(size_t)row * 512 + c] : hb[(size_t)row * 512 + (c - 512)];
    v[p] = val; s += val; q += val * val;
  }
  block_reduce2(s, q, scratch);
  float mean = s * (1.f / 1024.f);
  float var = q * (1.f / 1024.f) - mean * mean;
  float rs = rsqrtf(var + 1e-5f);
  #pragma unroll
  for (int p = 0; p < 4; p++) {
    int c = p * 256 + tid;
    hn[(size_t)row * 1024 + c] = (v[p] - mean) * rs * g[c] + be[c];
  }
}

// ---------------------------------------------------------------------------
// Generic tiled SGEMM. C[m][n] = act(bias[n] + sum_k A[m][k]*B(k,n))
// BT=true: B is [N,K] row-major; BT=false: B is [K,N] row-major.
// 64x64 tile, BK=16, 256 threads, 4x4 per thread. K must be multiple of 16.
// ---------------------------------------------------------------------------
template<bool BT, int ACT>
__global__ __launch_bounds__(256) void k_sgemm(
    const float* __restrict__ A, const float* __restrict__ B,
    const float* __restrict__ bias, float* __restrict__ C,
    int M, int N, int K, int lda, int ldb, int ldc)
{
  __shared__ float As[16][68];
  __shared__ float Bs[16][68];
  int tid = threadIdx.x;
  int tx = tid & 15, ty = tid >> 4;
  int n0g = blockIdx.x * 64, m0g = blockIdx.y * 64;
  float acc[4][4] = {{0.f}};

  for (int k0 = 0; k0 < K; k0 += 16) {
    {
      int m = tid >> 2, kq = (tid & 3) * 4;
      int mg = m0g + m;
      float v[4] = {0.f, 0.f, 0.f, 0.f};
      if (mg < M) {
        float4 t4 = *reinterpret_cast<const float4*>(A + (size_t)mg * lda + k0 + kq);
        v[0] = t4.x; v[1] = t4.y; v[2] = t4.z; v[3] = t4.w;
      }
      #pragma unroll
      for (int i = 0; i < 4; i++) As[kq + i][m] = v[i];
    }
    if (BT) {
      int n = tid >> 2, kq = (tid & 3) * 4;
      int ng = n0g + n;
      float v[4] = {0.f, 0.f, 0.f, 0.f};
      if (ng < N) {
        float4 t4 = *reinterpret_cast<const float4*>(B + (size_t)ng * ldb + k0 + kq);
        v[0] = t4.x; v[1] = t4.y; v[2] = t4.z; v[3] = t4.w;
      }
      #pragma unroll
      for (int i = 0; i < 4; i++) Bs[kq + i][n] = v[i];
    } else {
      int k = tid >> 4, n0 = (tid & 15) * 4;
      int ng = n0g + n0;
      float v[4] = {0.f, 0.f, 0.f, 0.f};
      if (ng < N) {
        float4 t4 = *reinterpret_cast<const float4*>(B + (size_t)(k0 + k) * ldb + ng);
        v[0] = t4.x; v[1] = t4.y; v[2] = t4.z; v[3] = t4.w;
      }
      #pragma unroll
      for (int i = 0; i < 4; i++) Bs[k][n0 + i] = v[i];
    }
    __syncthreads();
    #pragma unroll
    for (int k = 0; k < 16; k++) {
      float4 a4 = *reinterpret_cast<const float4*>(&As[k][ty * 4]);
      float4 b4 = *reinterpret_cast<const float4*>(&Bs[k][tx * 4]);
      float a[4] = {a4.x, a4.y, a4.z, a4.w};
      float bb[4] = {b4.x, b4.y, b4.z, b4.w};
      #pragma unroll
      for (int i = 0; i < 4; i++)
        #pragma unroll
        for (int j = 0; j < 4; j++)
          acc[i][j] += a[i] * bb[j];
    }
    __syncthreads();
  }
  #pragma unroll
  for (int i = 0; i < 4; i++) {
    int mg = m0g + ty * 4 + i;
    if (mg >= M) continue;
    #pragma unroll
    for (int j = 0; j < 4; j++) {
      int ng = n0g + tx * 4 + j;
      if (ng >= N) continue;
      float v = acc[i][j] + (bias ? bias[ng] : 0.f);
      if (ACT == 1) v = fmaxf(v, 0.f);
      C[(size_t)mg * ldc + ng] = v;
    }
  }
}

// ---------------------------------------------------------------------------
// K4: per (b,h) attention scores + softmax. Writes sc[(b*8+h)*640 + i*25+j].
// ---------------------------------------------------------------------------
__global__ __launch_bounds__(256) void k_scores(const float* __restrict__ qkv,
                                                float* __restrict__ sc)
{
  int b = blockIdx.x, h = blockIdx.y;
  __shared__ float qs[25][128];
  __shared__ float ks[25][129];
  __shared__ float ps[25][26];
  int tid = threadIdx.x;
  for (int idx = tid; idx < 3200; idx += 256) {
    int i = idx >> 7, d = idx & 127;
    const float* base = qkv + (size_t)(b * 25 + i) * 2048 + h * 128 + d;
    qs[i][d] = base[0];
    ks[i][d] = base[1024];
  }
  __syncthreads();
  const float scale = 0.08838834764831845f;  // 1/sqrt(128)
  for (int e = tid; e < 625; e += 256) {
    int i = e / 25, j = e % 25;
    float s = 0.f;
    for (int d = 0; d < 128; d++) s += qs[i][d] * ks[j][d];
    ps[i][j] = s * scale;
  }
  __syncthreads();
  if (tid < 25) {
    float mx = -1e30f;
    for (int j = 0; j < 25; j++) mx = fmaxf(mx, ps[tid][j]);
    float s = 0.f;
    for (int j = 0; j < 25; j++) { float ev = expf(ps[tid][j] - mx); ps[tid][j] = ev; s += ev; }
    float inv = 1.f / s;
    for (int j = 0; j < 25; j++) ps[tid][j] *= inv;
  }
  __syncthreads();
  float* out = sc + (size_t)(b * 8 + h) * 640;
  for (int e = tid; e < 625; e += 256) out[e] = ps[e / 25][e % 25];
}

// ---------------------------------------------------------------------------
// K5: generic per-row LayerNorm. C = PER*256. dst[row*dstStride + dstOff + c]
// ---------------------------------------------------------------------------
template<int PER>
__global__ __launch_bounds__(256) void k_ln_rows(
    const float* __restrict__ src, float* __restrict__ dst,
    const float* __restrict__ g, const float* __restrict__ be,
    int dstStride, int dstOff)
{
  __shared__ float scratch[8];
  int row = blockIdx.x, tid = threadIdx.x;
  const int C = PER * 256;
  float v[PER];
  float s = 0.f, q = 0.f;
  #pragma unroll
  for (int p = 0; p < PER; p++) {
    v[p] = src[(size_t)row * C + p * 256 + tid];
    s += v[p]; q += v[p] * v[p];
  }
  block_reduce2(s, q, scratch);
  float mean = s / (float)C;
  float var = q / (float)C - mean * mean;
  float rs = rsqrtf(var + 1e-5f);
  #pragma unroll
  for (int p = 0; p < PER; p++) {
    int c = p * 256 + tid;
    dst[(size_t)row * dstStride + dstOff + c] = (v[p] - mean) * rs * g[c] + be[c];
  }
}

// broadcast te into Xcat cols [512,1024)
__global__ __launch_bounds__(256) void k_bcast_te(const float* __restrict__ te,
                                                  float* __restrict__ xcat)
{
  int row = blockIdx.x, tid = threadIdx.x;
  int n = row % 25;
  xcat[(size_t)row * 1280 + 512 + tid] = te[n * 512 + tid];
  xcat[(size_t)row * 1280 + 768 + tid] = te[n * 512 + 256 + tid];
}

// ---------------------------------------------------------------------------
// K6: adjacency build (single block): mean attention, cosine emb-att, combine,
// case-amplification mask. adj[625].
// ---------------------------------------------------------------------------
__global__ __launch_bounds__(256) void k_adj(
    const float* __restrict__ sc, const float* __restrict__ te,
    const float* __restrict__ alpha_p, const float* __restrict__ dist,
    float* __restrict__ adj)
{
  __shared__ float als[625];
  __shared__ float ninv[25];
  __shared__ float scratch[8];
  __shared__ float mxs;
  int tid = threadIdx.x;

  for (int e = tid; e < 625; e += 256) {
    float s = 0.f;
    for (int gq = 0; gq < 256; gq++) s += sc[(size_t)gq * 640 + e];
    als[e] = s * (1.f / 256.f);
  }
  if (tid < 25) {
    float s = 0.f;
    const float* tp = te + tid * 512;
    for (int d = 0; d < 512; d++) s += tp[d] * tp[d];
    ninv[tid] = 1.f / fmaxf(sqrtf(s), 1e-8f);
  }
  __syncthreads();
  float alpha = alpha_p[0];
  for (int e = tid; e < 625; e += 256) {
    int i = e / 25, j = e % 25;
    float dt = 0.f;
    const float* ti = te + i * 512;
    const float* tj = te + j * 512;
    for (int d = 0; d < 512; d++) dt += ti[d] * tj[d];
    float emb = dt * ninv[i] * ninv[j];
    als[e] = (alpha * dist[e] + (1.f - alpha) * emb) * als[e];
  }
  __syncthreads();
  float lm = 0.f;
  for (int e = tid; e < 625; e += 256) {
    float a = fmaxf(als[e], 0.f);
    lm = fmaxf(lm, powf(a, 2.5f));
  }
  #pragma unroll
  for (int off = 32; off > 0; off >>= 1) lm = fmaxf(lm, __shfl_down(lm, off));
  int w = tid >> 6;
  if ((tid & 63) == 0) scratch[w] = lm;
  __syncthreads();
  if (tid == 0) {
    float m2 = scratch[0];
    for (int i = 1; i < 4; i++) m2 = fmaxf(m2, scratch[i]);
    mxs = m2;
  }
  __syncthreads();
  float mx = mxs;
  for (int e = tid; e < 625; e += 256) {
    float a = als[e];
    float m = powf(fmaxf(a, 0.f), 2.5f) / mx;
    adj[e] = (m >= 0.08f) ? a : 0.f;
  }
}

// ---------------------------------------------------------------------------
// K7: GCN adjacency mix: out[b,i,f] = epi(sum_j adj[j,i]*tmp[b,j,f] + bias[f])
// grid 800 (row = b*25+i), 256 threads (f).
// ---------------------------------------------------------------------------
template<int RESID, int LNORM>
__global__ __launch_bounds__(256) void k_mix(
    const float* __restrict__ adj, const float* __restrict__ tmp,
    const float* __restrict__ bias, const float* __restrict__ resid,
    const float* __restrict__ g, const float* __restrict__ be,
    float* __restrict__ out)
{
  __shared__ float adjs[25];
  __shared__ float scratch[8];
  int row = blockIdx.x;
  int b = row / 25, i = row % 25;
  int f = threadIdx.x;
  if (f < 25) adjs[f] = adj[f * 25 + i];
  __syncthreads();
  float acc = bias[f];
  const float* tp = tmp + (size_t)b * 25 * 256 + f;
  #pragma unroll 5
  for (int j = 0; j < 25; j++) acc += adjs[j] * tp[(size_t)j * 256];
  if (RESID) acc += resid[(size_t)row * 256 + f];
  float v = acc;
  if (LNORM) {
    float s = v, q = v * v;
    block_reduce2(s, q, scratch);
    float mean = s * (1.f / 256.f);
    float var = q * (1.f / 256.f) - mean * mean;
    v = (v - mean) * rsqrtf(var + 1e-5f) * g[f] + be[f];
  }
  out[(size_t)row * 256 + f] = fmaxf(v, 0.f);
}

// ---------------------------------------------------------------------------
// launch
// ---------------------------------------------------------------------------
extern "C" void kernel_launch(void* const* d_in, const int* in_sizes, int n_in,
                              void* d_out, int out_size, void* d_ws, size_t ws_size,
                              hipStream_t stream)
{
  (void)in_sizes; (void)n_in; (void)out_size; (void)ws_size;

  const float* x         = (const float*)d_in[0];
  const float* seq1_w1   = (const float*)d_in[1];
  const float* seq1_b1   = (const float*)d_in[2];
  const float* seq1_w2   = (const float*)d_in[3];
  const float* seq1_b2   = (const float*)d_in[4];
  const float* ln2_g     = (const float*)d_in[5];
  const float* ln2_b     = (const float*)d_in[6];
  const float* gru_wih_f = (const float*)d_in[7];
  const float* gru_whh_f = (const float*)d_in[8];
  const float* gru_bih_f = (const float*)d_in[9];
  const float* gru_bhh_f = (const float*)d_in[10];
  const float* gru_wih_b = (const float*)d_in[11];
  const float* gru_whh_b = (const float*)d_in[12];
  const float* gru_bih_b = (const float*)d_in[13];
  const float* gru_bhh_b = (const float*)d_in[14];
  const float* ln_g      = (const float*)d_in[15];
  const float* ln_b      = (const float*)d_in[16];
  const float* attn_in_w = (const float*)d_in[17];
  const float* attn_in_b = (const float*)d_in[18];
  const float* fc_ta_w   = (const float*)d_in[19];
  const float* fc_ta_b   = (const float*)d_in[20];
  const float* ln3_g     = (const float*)d_in[21];
  const float* ln3_b     = (const float*)d_in[22];
  const float* sem_embs  = (const float*)d_in[23];
  const float* sem_w     = (const float*)d_in[24];
  const float* sem_b     = (const float*)d_in[25];
  const float* lnsem_g   = (const float*)d_in[26];
  const float* lnsem_b   = (const float*)d_in[27];
  const float* att_alpha = (const float*)d_in[28];
  const float* dist_adj  = (const float*)d_in[29];
  const float* gcn_w0    = (const float*)d_in[30];
  const float* gcn_b0    = (const float*)d_in[31];
  const float* gcn_w1    = (const float*)d_in[32];
  const float* gcn_b1    = (const float*)d_in[33];
  const float* gcn_w2    = (const float*)d_in[34];
  const float* gcn_b2    = (const float*)d_in[35];
  const float* gln1_g    = (const float*)d_in[36];
  const float* gln1_b    = (const float*)d_in[37];
  const float* gln2_g    = (const float*)d_in[38];
  const float* gln2_b    = (const float*)d_in[39];
  const float* enc_ln_g  = (const float*)d_in[40];
  const float* enc_ln_b  = (const float*)d_in[41];
  const float* fc_w      = (const float*)d_in[42];
  const float* fc_b      = (const float*)d_in[43];

  float* w = (float*)d_ws;
  float* hseq = w + O_HSEQ;
  float* hbuf = w + O_HBUF;
  float* hn   = w + O_HN;
  float* qkv  = w + O_QKV;
  float* sc   = w + O_SC;
  float* adjw = w + O_ADJ;
  float* wr   = w + O_WR;
  float* tep  = w + O_TEP;
  float* te   = w + O_TE;
  float* xcat = w + O_XCAT;
  float* gtmp = w + O_GTMP;
  float* xg0  = w + O_XG0;
  float* xg1  = w + O_XG1;
  float* xg2  = w + O_XG2;

  // zero h0 (parity-0 block holds both directions contiguously)
  hipMemsetAsync(hbuf, 0, (size_t)2 * 409600 * sizeof(float), stream);

  // input MLP + LN
  k_mlp<<<48000 / 4, 256, 0, stream>>>(x, seq1_w1, seq1_b1, seq1_w2, seq1_b2,
                                       ln2_g, ln2_b, hseq);

  // bidirectional GRU, 60 steps
  for (int t = 0; t < SS; t++) {
    k_gru_step<<<dim3(16, 13, 2), 256, 0, stream>>>(
        hseq, gru_wih_f, gru_whh_f, gru_bih_f, gru_bhh_f,
        gru_wih_b, gru_whh_b, gru_bih_b, gru_bhh_b, hbuf, t);
  }

  // hn = LN(concat(hf, hb)); final hidden sits in parity 0
  k_ln_hn<<<800, 256, 0, stream>>>(hbuf, hbuf + 409600, ln_g, ln_b, hn);

  // q,k projection (skip v: unused). N=2048, ldc=2048.
  k_sgemm<true, 0><<<dim3(32, 13), 256, 0, stream>>>(
      hn, attn_in_w, attn_in_b, qkv, 800, 2048, 1024, 1024, 1024, 2048);

  // per (b,h) softmax attention
  k_scores<<<dim3(32, 8), 256, 0, stream>>>(qkv, sc);

  // semantic embedding projection + LN
  k_sgemm<false, 0><<<dim3(8, 1), 256, 0, stream>>>(
      sem_embs, sem_w, sem_b, tep, 25, 512, 768, 768, 512, 512);
  k_ln_rows<2><<<25, 256, 0, stream>>>(tep, te, lnsem_g, lnsem_b, 512, 0);

  // fc_ta + LN3 -> Xcat[:, 0:512]
  k_sgemm<false, 1><<<dim3(8, 13), 256, 0, stream>>>(
      hn, fc_ta_w, fc_ta_b, wr, 800, 512, 1024, 1024, 512, 512);
  k_ln_rows<2><<<800, 256, 0, stream>>>(wr, xcat, ln3_g, ln3_b, 1280, 0);
  k_bcast_te<<<800, 256, 0, stream>>>(te, xcat);

  // adjacency
  k_adj<<<1, 256, 0, stream>>>(sc, te, att_alpha, dist_adj, adjw);

  // GCN layer 0
  k_sgemm<false, 0><<<dim3(4, 13), 256, 0, stream>>>(
      xcat, gcn_w0, nullptr, gtmp, 800, 256, 1024, 1280, 256, 256);
  k_mix<0, 0><<<800, 256, 0, stream>>>(adjw, gtmp, gcn_b0, nullptr, nullptr, nullptr, xg0);
  // GCN layer 1
  k_sgemm<false, 0><<<dim3(4, 13), 256, 0, stream>>>(
      xg0, gcn_w1, nullptr, gtmp, 800, 256, 256, 256, 256, 256);
  k_mix<1, 1><<<800, 256, 0, stream>>>(adjw, gtmp, gcn_b1, xg0, gln1_g, gln1_b, xg1);
  // GCN layer 2
  k_sgemm<false, 0><<<dim3(4, 13), 256, 0, stream>>>(
      xg1, gcn_w2, nullptr, gtmp, 800, 256, 256, 256, 256, 256);
  k_mix<1, 1><<<800, 256, 0, stream>>>(adjw, gtmp, gcn_b2, xg1, gln2_g, gln2_b, xg2);

  // encoder LN -> Xcat[:, 1024:1280]
  k_ln_rows<1><<<800, 256, 0, stream>>>(xg2, xcat, enc_ln_g, enc_ln_b, 1280, 1024);

  // final fc + relu -> d_out
  k_sgemm<false, 1><<<dim3(8, 13), 256, 0, stream>>>(
      xcat, fc_w, fc_b, (float*)d_out, 800, 512, 1280, 1280, 512, 512);
}

// Round 2
// 2461.613 us; speedup vs baseline: 5.0634x; 5.0634x over previous
//
#include <hip/hip_runtime.h>
#include <hip/hip_bf16.h>
#include <math.h>

// ---------------------------------------------------------------------------
// Problem constants
// ---------------------------------------------------------------------------
#define BB 32
#define SS 60
#define NN_ 25
#define DIN 100
#define BN 800           // B*N
#define GRU_H 512
#define FDIM 1024        // TEMB+SEMB
#define CH 256
#define OUTD 512

typedef unsigned short ushort_t;
typedef float f32x4 __attribute__((ext_vector_type(4)));
typedef __bf16 bf16x8 __attribute__((ext_vector_type(8)));
typedef short s16x8 __attribute__((ext_vector_type(8)));

// workspace float offsets
static const size_t O_HSEQB = 0;          // bf16 48000*512 -> 12,288,000 floats
static const size_t O_WB    = 12288000;   // bf16 4*786432  -> 1,572,864 floats
static const size_t O_HF32  = 13860864;   // fp32 [2 par][2 dir][800*512] = 1,638,400
static const size_t O_HBB   = 15499264;   // bf16 same shape -> 819,200 floats
static const size_t O_HN    = 16318464;   // 800*1024
static const size_t O_QKV   = 17137664;   // 800*2048
static const size_t O_SC    = 18776064;   // 256*640
static const size_t O_ADJ   = 18939904;   // 640
static const size_t O_WR    = 18940544;   // 800*512
static const size_t O_TEP   = 19350144;   // 25*512
static const size_t O_TE    = 19362944;   // 25*512
static const size_t O_XCAT  = 19375744;   // 800*1280
static const size_t O_GTMP  = 20399744;   // 800*256
static const size_t O_XG0   = 20604544;   // 800*256
static const size_t O_XG1   = 20809344;   // 800*256
static const size_t O_XG2   = 21014144;   // 800*256

__device__ __forceinline__ ushort_t f2b(float v)
{
  __hip_bfloat16 b = __float2bfloat16(v);
  return *reinterpret_cast<ushort_t*>(&b);
}

// ---------------------------------------------------------------------------
// helpers
// ---------------------------------------------------------------------------
__device__ __forceinline__ void block_reduce2(float& s, float& q, float* scratch)
{
  __syncthreads();
  #pragma unroll
  for (int off = 32; off > 0; off >>= 1) {
    s += __shfl_down(s, off);
    q += __shfl_down(q, off);
  }
  int tid = threadIdx.x;
  int w = tid >> 6;
  if ((tid & 63) == 0) { scratch[w * 2] = s; scratch[w * 2 + 1] = q; }
  __syncthreads();
  if (tid == 0) {
    float ss = 0.f, qq = 0.f;
    int nw = blockDim.x >> 6;
    for (int i = 0; i < nw; i++) { ss += scratch[i * 2]; qq += scratch[i * 2 + 1]; }
    scratch[0] = ss; scratch[1] = qq;
  }
  __syncthreads();
  s = scratch[0]; q = scratch[1];
}

// ---------------------------------------------------------------------------
// K0: convert GRU weights to bf16. wb layout: [dir][ih(786432), hh(786432)]
// grid 3072, 256 threads.
// ---------------------------------------------------------------------------
__global__ __launch_bounds__(256) void k_cvt_w(
    const float* __restrict__ wih_f, const float* __restrict__ whh_f,
    const float* __restrict__ wih_b, const float* __restrict__ whh_b,
    ushort_t* __restrict__ wb)
{
  int i = blockIdx.x * 256 + threadIdx.x;   // 0..786431
  wb[i]           = f2b(wih_f[i]);
  wb[786432 + i]  = f2b(whh_f[i]);
  wb[1572864 + i] = f2b(wih_b[i]);
  wb[2359296 + i] = f2b(whh_b[i]);
}

// ---------------------------------------------------------------------------
// K1: fused input MLP (100->256 relu ->512 relu) + LayerNorm(512), bf16 out.
// grid: 48000/4 blocks, 256 threads. Writes hseqb[(bn*60+s)*512 + c]
// ---------------------------------------------------------------------------
__global__ __launch_bounds__(256) void k_mlp(
    const float* __restrict__ x,
    const float* __restrict__ w1, const float* __restrict__ b1,
    const float* __restrict__ w2, const float* __restrict__ b2,
    const float* __restrict__ g, const float* __restrict__ be,
    ushort_t* __restrict__ hseqb)
{
  const int R = 4;
  __shared__ float xs[R][DIN];
  __shared__ float h1s[R][256];
  __shared__ float h2s[R][512];
  __shared__ float scratch[8];
  int tid = threadIdx.x;
  int r0 = blockIdx.x * R;

  for (int idx = tid; idx < R * DIN; idx += 256) {
    int rr = idx / DIN, d = idx % DIN;
    int r = r0 + rr;
    int bn = r / SS, s = r % SS;
    int b = bn / NN_, n = bn % NN_;
    xs[rr][d] = x[(((size_t)b * SS + s) * NN_ + n) * DIN + d];
  }
  __syncthreads();
  {
    float acc[R];
    float bv = b1[tid];
    #pragma unroll
    for (int rr = 0; rr < R; rr++) acc[rr] = bv;
    for (int d = 0; d < DIN; d++) {
      float wv = w1[d * 256 + tid];
      #pragma unroll
      for (int rr = 0; rr < R; rr++) acc[rr] += xs[rr][d] * wv;
    }
    #pragma unroll
    for (int rr = 0; rr < R; rr++) h1s[rr][tid] = fmaxf(acc[rr], 0.f);
  }
  __syncthreads();
  {
    float acc0[R], acc1[R];
    float bv0 = b2[tid], bv1 = b2[tid + 256];
    #pragma unroll
    for (int rr = 0; rr < R; rr++) { acc0[rr] = bv0; acc1[rr] = bv1; }
    for (int d = 0; d < 256; d++) {
      float w0 = w2[d * 512 + tid];
      float w1v = w2[d * 512 + tid + 256];
      #pragma unroll
      for (int rr = 0; rr < R; rr++) {
        float h = h1s[rr][d];
        acc0[rr] += h * w0;
        acc1[rr] += h * w1v;
      }
    }
    #pragma unroll
    for (int rr = 0; rr < R; rr++) {
      h2s[rr][tid] = fmaxf(acc0[rr], 0.f);
      h2s[rr][tid + 256] = fmaxf(acc1[rr], 0.f);
    }
  }
  __syncthreads();
  for (int rr = 0; rr < R; rr++) {
    float v0 = h2s[rr][tid], v1 = h2s[rr][tid + 256];
    float s = v0 + v1, q = v0 * v0 + v1 * v1;
    block_reduce2(s, q, scratch);
    float mean = s * (1.f / 512.f);
    float var = q * (1.f / 512.f) - mean * mean;
    float rs = rsqrtf(var + 1e-5f);
    size_t r = (size_t)(r0 + rr);
    hseqb[r * 512 + tid] = f2b((v0 - mean) * rs * g[tid] + be[tid]);
    hseqb[r * 512 + tid + 256] = f2b((v1 - mean) * rs * g[tid + 256] + be[tid + 256]);
  }
}

// ---------------------------------------------------------------------------
// K2: one GRU step, MFMA bf16. Both dirs via blockIdx.z.
// grid: (8 j-tiles, 13 m-tiles, 2 dirs), 256 threads (4 waves, 2x2 of 32x32).
// Gate sums in fp32 AGPR via mfma_f32_16x16x32_bf16; fused gate epilogue.
// ---------------------------------------------------------------------------
__global__ __launch_bounds__(256) void k_gru_mfma(
    const ushort_t* __restrict__ hseqb, const ushort_t* __restrict__ wb,
    const float* __restrict__ bih_f, const float* __restrict__ bhh_f,
    const float* __restrict__ bih_b, const float* __restrict__ bhh_b,
    float* __restrict__ hf32, ushort_t* __restrict__ hbb, int t)
{
  // LDS: row stride 40 elems (80B) -> 16B-aligned b128 access, 2-way bank alias (free)
  __shared__ __align__(16) ushort_t Xs[64][40];
  __shared__ __align__(16) ushort_t Hs[64][40];
  __shared__ __align__(16) ushort_t Ws[6][64][40];

  const int dir = blockIdx.z;
  const ushort_t* __restrict__ wih = wb + (size_t)dir * 1572864;
  const ushort_t* __restrict__ whh = wih + 786432;
  const float* __restrict__ bih = dir ? bih_b : bih_f;
  const float* __restrict__ bhh = dir ? bhh_b : bhh_f;
  const int xt = dir ? (SS - 1 - t) : t;
  const size_t par0 = (size_t)(t & 1) * 819200 + (size_t)dir * 409600;
  const size_t par1 = (size_t)((t + 1) & 1) * 819200 + (size_t)dir * 409600;
  const float* __restrict__ hprevf = hf32 + par0;
  float* __restrict__ hnewf = hf32 + par1;
  const ushort_t* __restrict__ hprevb = hbb + par0;
  ushort_t* __restrict__ hnewb = hbb + par1;

  const int tid = threadIdx.x;
  const int j0g = blockIdx.x * 64;
  const int m0g = blockIdx.y * 64;

  // staging: row = tid>>2 (0..63), k-group = (tid&3)*8
  const int srow = tid >> 2;
  const int skg = (tid & 3) * 8;
  const int smg = m0g + srow;

  const int wid = tid >> 6;
  const int l = tid & 63;
  const int lr = l & 15;       // A row / B col / C col
  const int lg = l >> 4;       // k-group / C row-group
  const int mbase = (wid >> 1) * 32;
  const int nbase = (wid & 1) * 32;

  f32x4 accr[2][2] = {};
  f32x4 accz[2][2] = {};
  f32x4 accin[2][2] = {};
  f32x4 acchn[2][2] = {};

  for (int k0 = 0; k0 < 512; k0 += 32) {
    s16x8 xv = {0,0,0,0,0,0,0,0};
    s16x8 hv = {0,0,0,0,0,0,0,0};
    if (smg < BN) {
      xv = *reinterpret_cast<const s16x8*>(hseqb + ((size_t)smg * SS + xt) * 512 + k0 + skg);
      hv = *reinterpret_cast<const s16x8*>(hprevb + (size_t)smg * 512 + k0 + skg);
    }
    *reinterpret_cast<s16x8*>(&Xs[srow][skg]) = xv;
    *reinterpret_cast<s16x8*>(&Hs[srow][skg]) = hv;
    #pragma unroll
    for (int tt = 0; tt < 6; tt++) {
      const ushort_t* src = (tt < 3) ? wih : whh;
      int gate = (tt < 3) ? tt : tt - 3;
      int jglob = gate * 512 + j0g + srow;
      s16x8 wv = *reinterpret_cast<const s16x8*>(src + (size_t)jglob * 512 + k0 + skg);
      *reinterpret_cast<s16x8*>(&Ws[tt][srow][skg]) = wv;
    }
    __syncthreads();

    bf16x8 xA[2], hA[2];
    #pragma unroll
    for (int mi = 0; mi < 2; mi++) {
      xA[mi] = *reinterpret_cast<const bf16x8*>(&Xs[mbase + mi * 16 + lr][lg * 8]);
      hA[mi] = *reinterpret_cast<const bf16x8*>(&Hs[mbase + mi * 16 + lr][lg * 8]);
    }
    #pragma unroll
    for (int ni = 0; ni < 2; ni++) {
      const int wrow = nbase + ni * 16 + lr;
      bf16x8 bWr = *reinterpret_cast<const bf16x8*>(&Ws[0][wrow][lg * 8]);
      bf16x8 bWz = *reinterpret_cast<const bf16x8*>(&Ws[1][wrow][lg * 8]);
      bf16x8 bWn = *reinterpret_cast<const bf16x8*>(&Ws[2][wrow][lg * 8]);
      bf16x8 bVr = *reinterpret_cast<const bf16x8*>(&Ws[3][wrow][lg * 8]);
      bf16x8 bVz = *reinterpret_cast<const bf16x8*>(&Ws[4][wrow][lg * 8]);
      bf16x8 bVn = *reinterpret_cast<const bf16x8*>(&Ws[5][wrow][lg * 8]);
      #pragma unroll
      for (int mi = 0; mi < 2; mi++) {
        accr[mi][ni]  = __builtin_amdgcn_mfma_f32_16x16x32_bf16(xA[mi], bWr, accr[mi][ni], 0, 0, 0);
        accr[mi][ni]  = __builtin_amdgcn_mfma_f32_16x16x32_bf16(hA[mi], bVr, accr[mi][ni], 0, 0, 0);
        accz[mi][ni]  = __builtin_amdgcn_mfma_f32_16x16x32_bf16(xA[mi], bWz, accz[mi][ni], 0, 0, 0);
        accz[mi][ni]  = __builtin_amdgcn_mfma_f32_16x16x32_bf16(hA[mi], bVz, accz[mi][ni], 0, 0, 0);
        accin[mi][ni] = __builtin_amdgcn_mfma_f32_16x16x32_bf16(xA[mi], bWn, accin[mi][ni], 0, 0, 0);
        acchn[mi][ni] = __builtin_amdgcn_mfma_f32_16x16x32_bf16(hA[mi], bVn, acchn[mi][ni], 0, 0, 0);
      }
    }
    __syncthreads();
  }

  // epilogue: C frag mapping col = lane&15, row = 4*(lane>>4)+reg (m89-verified)
  #pragma unroll
  for (int mi = 0; mi < 2; mi++) {
    #pragma unroll
    for (int r = 0; r < 4; r++) {
      int m = m0g + mbase + mi * 16 + lg * 4 + r;
      if (m >= BN) continue;
      #pragma unroll
      for (int ni = 0; ni < 2; ni++) {
        int j = j0g + nbase + ni * 16 + lr;
        float sr = accr[mi][ni][r] + bih[j] + bhh[j];
        float sz = accz[mi][ni][r] + bih[512 + j] + bhh[512 + j];
        float rg = 1.f / (1.f + expf(-sr));
        float zg = 1.f / (1.f + expf(-sz));
        float ng = tanhf(accin[mi][ni][r] + bih[1024 + j] + rg * (acchn[mi][ni][r] + bhh[1024 + j]));
        float hp = hprevf[(size_t)m * 512 + j];
        float hvv = (1.f - zg) * ng + zg * hp;
        hnewf[(size_t)m * 512 + j] = hvv;
        hnewb[(size_t)m * 512 + j] = f2b(hvv);
      }
    }
  }
}

// ---------------------------------------------------------------------------
// K3: hn = LN(concat(hf, hb)) over 1024. grid 800, 256 threads.
// ---------------------------------------------------------------------------
__global__ __launch_bounds__(256) void k_ln_hn(
    const float* __restrict__ hf, const float* __restrict__ hb,
    const float* __restrict__ g, const float* __restrict__ be,
    float* __restrict__ hn)
{
  __shared__ float scratch[8];
  int row = blockIdx.x, tid = threadIdx.x;
  float v[4];
  float s = 0.f, q = 0.f;
  #pragma unroll
  for (int p = 0; p < 4; p++) {
    int c = p * 256 + tid;
    float val = (c < 512) ? hf[(size_t)row * 512 + c] : hb[(size_t)row * 512 + (c - 512)];
    v[p] = val; s += val; q += val * val;
  }
  block_reduce2(s, q, scratch);
  float mean = s * (1.f / 1024.f);
  float var = q * (1.f / 1024.f) - mean * mean;
  float rs = rsqrtf(var + 1e-5f);
  #pragma unroll
  for (int p = 0; p < 4; p++) {
    int c = p * 256 + tid;
    hn[(size_t)row * 1024 + c] = (v[p] - mean) * rs * g[c] + be[c];
  }
}

// ---------------------------------------------------------------------------
// Generic tiled SGEMM. C[m][n] = act(bias[n] + sum_k A[m][k]*B(k,n))
// BT=true: B is [N,K] row-major; BT=false: B is [K,N] row-major.
// 64x64 tile, BK=16, 256 threads, 4x4 per thread. K must be multiple of 16.
// ---------------------------------------------------------------------------
template<bool BT, int ACT>
__global__ __launch_bounds__(256) void k_sgemm(
    const float* __restrict__ A, const float* __restrict__ B,
    const float* __restrict__ bias, float* __restrict__ C,
    int M, int N, int K, int lda, int ldb, int ldc)
{
  __shared__ float As[16][68];
  __shared__ float Bs[16][68];
  int tid = threadIdx.x;
  int tx = tid & 15, ty = tid >> 4;
  int n0g = blockIdx.x * 64, m0g = blockIdx.y * 64;
  float acc[4][4] = {{0.f}};

  for (int k0 = 0; k0 < K; k0 += 16) {
    {
      int m = tid >> 2, kq = (tid & 3) * 4;
      int mg = m0g + m;
      float v[4] = {0.f, 0.f, 0.f, 0.f};
      if (mg < M) {
        float4 t4 = *reinterpret_cast<const float4*>(A + (size_t)mg * lda + k0 + kq);
        v[0] = t4.x; v[1] = t4.y; v[2] = t4.z; v[3] = t4.w;
      }
      #pragma unroll
      for (int i = 0; i < 4; i++) As[kq + i][m] = v[i];
    }
    if (BT) {
      int n = tid >> 2, kq = (tid & 3) * 4;
      int ng = n0g + n;
      float v[4] = {0.f, 0.f, 0.f, 0.f};
      if (ng < N) {
        float4 t4 = *reinterpret_cast<const float4*>(B + (size_t)ng * ldb + k0 + kq);
        v[0] = t4.x; v[1] = t4.y; v[2] = t4.z; v[3] = t4.w;
      }
      #pragma unroll
      for (int i = 0; i < 4; i++) Bs[kq + i][n] = v[i];
    } else {
      int k = tid >> 4, n0 = (tid & 15) * 4;
      int ng = n0g + n0;
      float v[4] = {0.f, 0.f, 0.f, 0.f};
      if (ng < N) {
        float4 t4 = *reinterpret_cast<const float4*>(B + (size_t)(k0 + k) * ldb + ng);
        v[0] = t4.x; v[1] = t4.y; v[2] = t4.z; v[3] = t4.w;
      }
      #pragma unroll
      for (int i = 0; i < 4; i++) Bs[k][n0 + i] = v[i];
    }
    __syncthreads();
    #pragma unroll
    for (int k = 0; k < 16; k++) {
      float4 a4 = *reinterpret_cast<const float4*>(&As[k][ty * 4]);
      float4 b4 = *reinterpret_cast<const float4*>(&Bs[k][tx * 4]);
      float a[4] = {a4.x, a4.y, a4.z, a4.w};
      float bb[4] = {b4.x, b4.y, b4.z, b4.w};
      #pragma unroll
      for (int i = 0; i < 4; i++)
        #pragma unroll
        for (int j = 0; j < 4; j++)
          acc[i][j] += a[i] * bb[j];
    }
    __syncthreads();
  }
  #pragma unroll
  for (int i = 0; i < 4; i++) {
    int mg = m0g + ty * 4 + i;
    if (mg >= M) continue;
    #pragma unroll
    for (int j = 0; j < 4; j++) {
      int ng = n0g + tx * 4 + j;
      if (ng >= N) continue;
      float v = acc[i][j] + (bias ? bias[ng] : 0.f);
      if (ACT == 1) v = fmaxf(v, 0.f);
      C[(size_t)mg * ldc + ng] = v;
    }
  }
}

// ---------------------------------------------------------------------------
// K4: per (b,h) attention scores + softmax. Writes sc[(b*8+h)*640 + i*25+j].
// ---------------------------------------------------------------------------
__global__ __launch_bounds__(256) void k_scores(const float* __restrict__ qkv,
                                                float* __restrict__ sc)
{
  int b = blockIdx.x, h = blockIdx.y;
  __shared__ float qs[25][128];
  __shared__ float ks[25][129];
  __shared__ float ps[25][26];
  int tid = threadIdx.x;
  for (int idx = tid; idx < 3200; idx += 256) {
    int i = idx >> 7, d = idx & 127;
    const float* base = qkv + (size_t)(b * 25 + i) * 2048 + h * 128 + d;
    qs[i][d] = base[0];
    ks[i][d] = base[1024];
  }
  __syncthreads();
  const float scale = 0.08838834764831845f;  // 1/sqrt(128)
  for (int e = tid; e < 625; e += 256) {
    int i = e / 25, j = e % 25;
    float s = 0.f;
    for (int d = 0; d < 128; d++) s += qs[i][d] * ks[j][d];
    ps[i][j] = s * scale;
  }
  __syncthreads();
  if (tid < 25) {
    float mx = -1e30f;
    for (int j = 0; j < 25; j++) mx = fmaxf(mx, ps[tid][j]);
    float s = 0.f;
    for (int j = 0; j < 25; j++) { float ev = expf(ps[tid][j] - mx); ps[tid][j] = ev; s += ev; }
    float inv = 1.f / s;
    for (int j = 0; j < 25; j++) ps[tid][j] *= inv;
  }
  __syncthreads();
  float* out = sc + (size_t)(b * 8 + h) * 640;
  for (int e = tid; e < 625; e += 256) out[e] = ps[e / 25][e % 25];
}

// ---------------------------------------------------------------------------
// K5: generic per-row LayerNorm. C = PER*256. dst[row*dstStride + dstOff + c]
// ---------------------------------------------------------------------------
template<int PER>
__global__ __launch_bounds__(256) void k_ln_rows(
    const float* __restrict__ src, float* __restrict__ dst,
    const float* __restrict__ g, const float* __restrict__ be,
    int dstStride, int dstOff)
{
  __shared__ float scratch[8];
  int row = blockIdx.x, tid = threadIdx.x;
  const int C = PER * 256;
  float v[PER];
  float s = 0.f, q = 0.f;
  #pragma unroll
  for (int p = 0; p < PER; p++) {
    v[p] = src[(size_t)row * C + p * 256 + tid];
    s += v[p]; q += v[p] * v[p];
  }
  block_reduce2(s, q, scratch);
  float mean = s / (float)C;
  float var = q / (float)C - mean * mean;
  float rs = rsqrtf(var + 1e-5f);
  #pragma unroll
  for (int p = 0; p < PER; p++) {
    int c = p * 256 + tid;
    dst[(size_t)row * dstStride + dstOff + c] = (v[p] - mean) * rs * g[c] + be[c];
  }
}

// broadcast te into Xcat cols [512,1024)
__global__ __launch_bounds__(256) void k_bcast_te(const float* __restrict__ te,
                                                  float* __restrict__ xcat)
{
  int row = blockIdx.x, tid = threadIdx.x;
  int n = row % 25;
  xcat[(size_t)row * 1280 + 512 + tid] = te[n * 512 + tid];
  xcat[(size_t)row * 1280 + 768 + tid] = te[n * 512 + 256 + tid];
}

// ---------------------------------------------------------------------------
// K6: adjacency build (single block)
// ---------------------------------------------------------------------------
__global__ __launch_bounds__(256) void k_adj(
    const float* __restrict__ sc, const float* __restrict__ te,
    const float* __restrict__ alpha_p, const float* __restrict__ dist,
    float* __restrict__ adj)
{
  __shared__ float als[625];
  __shared__ float ninv[25];
  __shared__ float scratch[8];
  __shared__ float mxs;
  int tid = threadIdx.x;

  for (int e = tid; e < 625; e += 256) {
    float s = 0.f;
    for (int gq = 0; gq < 256; gq++) s += sc[(size_t)gq * 640 + e];
    als[e] = s * (1.f / 256.f);
  }
  if (tid < 25) {
    float s = 0.f;
    const float* tp = te + tid * 512;
    for (int d = 0; d < 512; d++) s += tp[d] * tp[d];
    ninv[tid] = 1.f / fmaxf(sqrtf(s), 1e-8f);
  }
  __syncthreads();
  float alpha = alpha_p[0];
  for (int e = tid; e < 625; e += 256) {
    int i = e / 25, j = e % 25;
    float dt = 0.f;
    const float* ti = te + i * 512;
    const float* tj = te + j * 512;
    for (int d = 0; d < 512; d++) dt += ti[d] * tj[d];
    float emb = dt * ninv[i] * ninv[j];
    als[e] = (alpha * dist[e] + (1.f - alpha) * emb) * als[e];
  }
  __syncthreads();
  float lm = 0.f;
  for (int e = tid; e < 625; e += 256) {
    float a = fmaxf(als[e], 0.f);
    lm = fmaxf(lm, powf(a, 2.5f));
  }
  #pragma unroll
  for (int off = 32; off > 0; off >>= 1) lm = fmaxf(lm, __shfl_down(lm, off));
  int w = tid >> 6;
  if ((tid & 63) == 0) scratch[w] = lm;
  __syncthreads();
  if (tid == 0) {
    float m2 = scratch[0];
    for (int i = 1; i < 4; i++) m2 = fmaxf(m2, scratch[i]);
    mxs = m2;
  }
  __syncthreads();
  float mx = mxs;
  for (int e = tid; e < 625; e += 256) {
    float a = als[e];
    float m = powf(fmaxf(a, 0.f), 2.5f) / mx;
    adj[e] = (m >= 0.08f) ? a : 0.f;
  }
}

// ---------------------------------------------------------------------------
// K7: GCN adjacency mix
// ---------------------------------------------------------------------------
template<int RESID, int LNORM>
__global__ __launch_bounds__(256) void k_mix(
    const float* __restrict__ adj, const float* __restrict__ tmp,
    const float* __restrict__ bias, const float* __restrict__ resid,
    const float* __restrict__ g, const float* __restrict__ be,
    float* __restrict__ out)
{
  __shared__ float adjs[25];
  __shared__ float scratch[8];
  int row = blockIdx.x;
  int b = row / 25, i = row % 25;
  int f = threadIdx.x;
  if (f < 25) adjs[f] = adj[f * 25 + i];
  __syncthreads();
  float acc = bias[f];
  const float* tp = tmp + (size_t)b * 25 * 256 + f;
  #pragma unroll 5
  for (int j = 0; j < 25; j++) acc += adjs[j] * tp[(size_t)j * 256];
  if (RESID) acc += resid[(size_t)row * 256 + f];
  float v = acc;
  if (LNORM) {
    float s = v, q = v * v;
    block_reduce2(s, q, scratch);
    float mean = s * (1.f / 256.f);
    float var = q * (1.f / 256.f) - mean * mean;
    v = (v - mean) * rsqrtf(var + 1e-5f) * g[f] + be[f];
  }
  out[(size_t)row * 256 + f] = fmaxf(v, 0.f);
}

// ---------------------------------------------------------------------------
// launch
// ---------------------------------------------------------------------------
extern "C" void kernel_launch(void* const* d_in, const int* in_sizes, int n_in,
                              void* d_out, int out_size, void* d_ws, size_t ws_size,
                              hipStream_t stream)
{
  (void)in_sizes; (void)n_in; (void)out_size; (void)ws_size;

  const float* x         = (const float*)d_in[0];
  const float* seq1_w1   = (const float*)d_in[1];
  const float* seq1_b1   = (const float*)d_in[2];
  const float* seq1_w2   = (const float*)d_in[3];
  const float* seq1_b2   = (const float*)d_in[4];
  const float* ln2_g     = (const float*)d_in[5];
  const float* ln2_b     = (const float*)d_in[6];
  const float* gru_wih_f = (const float*)d_in[7];
  const float* gru_whh_f = (const float*)d_in[8];
  const float* gru_bih_f = (const float*)d_in[9];
  const float* gru_bhh_f = (const float*)d_in[10];
  const float* gru_wih_b = (const float*)d_in[11];
  const float* gru_whh_b = (const float*)d_in[12];
  const float* gru_bih_b = (const float*)d_in[13];
  const float* gru_bhh_b = (const float*)d_in[14];
  const float* ln_g      = (const float*)d_in[15];
  const float* ln_b      = (const float*)d_in[16];
  const float* attn_in_w = (const float*)d_in[17];
  const float* attn_in_b = (const float*)d_in[18];
  const float* fc_ta_w   = (const float*)d_in[19];
  const float* fc_ta_b   = (const float*)d_in[20];
  const float* ln3_g     = (const float*)d_in[21];
  const float* ln3_b     = (const float*)d_in[22];
  const float* sem_embs  = (const float*)d_in[23];
  const float* sem_w     = (const float*)d_in[24];
  const float* sem_b     = (const float*)d_in[25];
  const float* lnsem_g   = (const float*)d_in[26];
  const float* lnsem_b   = (const float*)d_in[27];
  const float* att_alpha = (const float*)d_in[28];
  const float* dist_adj  = (const float*)d_in[29];
  const float* gcn_w0    = (const float*)d_in[30];
  const float* gcn_b0    = (const float*)d_in[31];
  const float* gcn_w1    = (const float*)d_in[32];
  const float* gcn_b1    = (const float*)d_in[33];
  const float* gcn_w2    = (const float*)d_in[34];
  const float* gcn_b2    = (const float*)d_in[35];
  const float* gln1_g    = (const float*)d_in[36];
  const float* gln1_b    = (const float*)d_in[37];
  const float* gln2_g    = (const float*)d_in[38];
  const float* gln2_b    = (const float*)d_in[39];
  const float* enc_ln_g  = (const float*)d_in[40];
  const float* enc_ln_b  = (const float*)d_in[41];
  const float* fc_w      = (const float*)d_in[42];
  const float* fc_b      = (const float*)d_in[43];

  float* w = (float*)d_ws;
  ushort_t* hseqb = (ushort_t*)(w + O_HSEQB);
  ushort_t* wb    = (ushort_t*)(w + O_WB);
  float* hf32 = w + O_HF32;
  ushort_t* hbb = (ushort_t*)(w + O_HBB);
  float* hn   = w + O_HN;
  float* qkv  = w + O_QKV;
  float* sc   = w + O_SC;
  float* adjw = w + O_ADJ;
  float* wr   = w + O_WR;
  float* tep  = w + O_TEP;
  float* te   = w + O_TE;
  float* xcat = w + O_XCAT;
  float* gtmp = w + O_GTMP;
  float* xg0  = w + O_XG0;
  float* xg1  = w + O_XG1;
  float* xg2  = w + O_XG2;

  // zero h0 (parity-0 block holds both directions contiguously)
  hipMemsetAsync(hf32, 0, (size_t)819200 * sizeof(float), stream);
  hipMemsetAsync(hbb, 0, (size_t)819200 * sizeof(ushort_t), stream);

  // weights -> bf16
  k_cvt_w<<<3072, 256, 0, stream>>>(gru_wih_f, gru_whh_f, gru_wih_b, gru_whh_b, wb);

  // input MLP + LN (bf16 out)
  k_mlp<<<48000 / 4, 256, 0, stream>>>(x, seq1_w1, seq1_b1, seq1_w2, seq1_b2,
                                       ln2_g, ln2_b, hseqb);

  // bidirectional GRU, 60 steps (MFMA)
  for (int t = 0; t < SS; t++) {
    k_gru_mfma<<<dim3(8, 13, 2), 256, 0, stream>>>(
        hseqb, wb, gru_bih_f, gru_bhh_f, gru_bih_b, gru_bhh_b, hf32, hbb, t);
  }

  // hn = LN(concat(hf, hb)); final hidden sits in parity 0
  k_ln_hn<<<800, 256, 0, stream>>>(hf32, hf32 + 409600, ln_g, ln_b, hn);

  // q,k projection (skip v: unused). N=2048, ldc=2048.
  k_sgemm<true, 0><<<dim3(32, 13), 256, 0, stream>>>(
      hn, attn_in_w, attn_in_b, qkv, 800, 2048, 1024, 1024, 1024, 2048);

  // per (b,h) softmax attention
  k_scores<<<dim3(32, 8), 256, 0, stream>>>(qkv, sc);

  // semantic embedding projection + LN
  k_sgemm<false, 0><<<dim3(8, 1), 256, 0, stream>>>(
      sem_embs, sem_w, sem_b, tep, 25, 512, 768, 768, 512, 512);
  k_ln_rows<2><<<25, 256, 0, stream>>>(tep, te, lnsem_g, lnsem_b, 512, 0);

  // fc_ta + LN3 -> Xcat[:, 0:512]
  k_sgemm<false, 1><<<dim3(8, 13), 256, 0, stream>>>(
      hn, fc_ta_w, fc_ta_b, wr, 800, 512, 1024, 1024, 512, 512);
  k_ln_rows<2><<<800, 256, 0, stream>>>(wr, xcat, ln3_g, ln3_b, 1280, 0);
  k_bcast_te<<<800, 256, 0, stream>>>(te, xcat);

  // adjacency
  k_adj<<<1, 256, 0, stream>>>(sc, te, att_alpha, dist_adj, adjw);

  // GCN layer 0
  k_sgemm<false, 0><<<dim3(4, 13), 256, 0, stream>>>(
      xcat, gcn_w0, nullptr, gtmp, 800, 256, 1024, 1280, 256, 256);
  k_mix<0, 0><<<800, 256, 0, stream>>>(adjw, gtmp, gcn_b0, nullptr, nullptr, nullptr, xg0);
  // GCN layer 1
  k_sgemm<false, 0><<<dim3(4, 13), 256, 0, stream>>>(
      xg0, gcn_w1, nullptr, gtmp, 800, 256, 256, 256, 256, 256);
  k_mix<1, 1><<<800, 256, 0, stream>>>(adjw, gtmp, gcn_b1, xg0, gln1_g, gln1_b, xg1);
  // GCN layer 2
  k_sgemm<false, 0><<<dim3(4, 13), 256, 0, stream>>>(
      xg1, gcn_w2, nullptr, gtmp, 800, 256, 256, 256, 256, 256);
  k_mix<1, 1><<<800, 256, 0, stream>>>(adjw, gtmp, gcn_b2, xg1, gln2_g, gln2_b, xg2);

  // encoder LN -> Xcat[:, 1024:1280]
  k_ln_rows<1><<<800, 256, 0, stream>>>(xg2, xcat, enc_ln_g, enc_ln_b, 1280, 1024);

  // final fc + relu -> d_out
  k_sgemm<false, 1><<<dim3(8, 13), 256, 0, stream>>>(
      xcat, fc_w, fc_b, (float*)d_out, 800, 512, 1280, 1280, 512, 512);
}

// Round 3
// 2219.867 us; speedup vs baseline: 5.6148x; 1.1089x over previous
//
#include <hip/hip_runtime.h>
#include <hip/hip_bf16.h>
#include <math.h>

// ---------------------------------------------------------------------------
// Problem constants
// ---------------------------------------------------------------------------
#define BB 32
#define SS 60
#define NN_ 25
#define DIN 100
#define BN 800           // B*N
#define GRU_H 512
#define FDIM 1024        // TEMB+SEMB
#define CH 256
#define OUTD 512

typedef unsigned short ushort_t;
typedef float f32x4 __attribute__((ext_vector_type(4)));
typedef __bf16 bf16x8 __attribute__((ext_vector_type(8)));
typedef short s16x8 __attribute__((ext_vector_type(8)));

// workspace float offsets
static const size_t O_HSEQB = 0;          // bf16 48000*512 -> 12,288,000 floats
static const size_t O_WB    = 12288000;   // bf16 4*786432  -> 1,572,864 floats
static const size_t O_HF32  = 13860864;   // fp32 [2 par][2 dir][800*512] = 1,638,400
static const size_t O_HBB   = 15499264;   // bf16 same shape -> 819,200 floats
static const size_t O_HN    = 16318464;   // 800*1024
static const size_t O_QKV   = 17137664;   // 800*2048
static const size_t O_SC    = 18776064;   // 256*640
static const size_t O_ADJ   = 18939904;   // 640
static const size_t O_WR    = 18940544;   // 800*512
static const size_t O_TEP   = 19350144;   // 25*512
static const size_t O_TE    = 19362944;   // 25*512
static const size_t O_XCAT  = 19375744;   // 800*1280
static const size_t O_GTMP  = 20399744;   // 800*256
static const size_t O_XG0   = 20604544;   // 800*256
static const size_t O_XG1   = 20809344;   // 800*256
static const size_t O_XG2   = 21014144;   // 800*256

__device__ __forceinline__ ushort_t f2b(float v)
{
  __hip_bfloat16 b = __float2bfloat16(v);
  return *reinterpret_cast<ushort_t*>(&b);
}

__device__ __forceinline__ float sig_fast(float v)
{
  return 1.f / (1.f + __expf(-v));
}
__device__ __forceinline__ float tanh_fast(float v)
{
  // exact identity: tanh(x) = 1 - 2/(1+e^{2x}); overflow-safe (inf -> 1, 0 -> -1)
  return 1.f - 2.f / (1.f + __expf(2.f * v));
}

// ---------------------------------------------------------------------------
// helpers
// ---------------------------------------------------------------------------
__device__ __forceinline__ void block_reduce2(float& s, float& q, float* scratch)
{
  __syncthreads();
  #pragma unroll
  for (int off = 32; off > 0; off >>= 1) {
    s += __shfl_down(s, off);
    q += __shfl_down(q, off);
  }
  int tid = threadIdx.x;
  int w = tid >> 6;
  if ((tid & 63) == 0) { scratch[w * 2] = s; scratch[w * 2 + 1] = q; }
  __syncthreads();
  if (tid == 0) {
    float ss = 0.f, qq = 0.f;
    int nw = blockDim.x >> 6;
    for (int i = 0; i < nw; i++) { ss += scratch[i * 2]; qq += scratch[i * 2 + 1]; }
    scratch[0] = ss; scratch[1] = qq;
  }
  __syncthreads();
  s = scratch[0]; q = scratch[1];
}

// ---------------------------------------------------------------------------
// K0: convert GRU weights to bf16. wb layout: [dir][ih(786432), hh(786432)]
// ---------------------------------------------------------------------------
__global__ __launch_bounds__(256) void k_cvt_w(
    const float* __restrict__ wih_f, const float* __restrict__ whh_f,
    const float* __restrict__ wih_b, const float* __restrict__ whh_b,
    ushort_t* __restrict__ wb)
{
  int i = blockIdx.x * 256 + threadIdx.x;   // 0..786431
  wb[i]           = f2b(wih_f[i]);
  wb[786432 + i]  = f2b(whh_f[i]);
  wb[1572864 + i] = f2b(wih_b[i]);
  wb[2359296 + i] = f2b(whh_b[i]);
}

// ---------------------------------------------------------------------------
// K1: fused input MLP (100->256 relu ->512 relu) + LayerNorm(512), bf16 out.
// ---------------------------------------------------------------------------
__global__ __launch_bounds__(256) void k_mlp(
    const float* __restrict__ x,
    const float* __restrict__ w1, const float* __restrict__ b1,
    const float* __restrict__ w2, const float* __restrict__ b2,
    const float* __restrict__ g, const float* __restrict__ be,
    ushort_t* __restrict__ hseqb)
{
  const int R = 4;
  __shared__ float xs[R][DIN];
  __shared__ float h1s[R][256];
  __shared__ float h2s[R][512];
  __shared__ float scratch[8];
  int tid = threadIdx.x;
  int r0 = blockIdx.x * R;

  for (int idx = tid; idx < R * DIN; idx += 256) {
    int rr = idx / DIN, d = idx % DIN;
    int r = r0 + rr;
    int bn = r / SS, s = r % SS;
    int b = bn / NN_, n = bn % NN_;
    xs[rr][d] = x[(((size_t)b * SS + s) * NN_ + n) * DIN + d];
  }
  __syncthreads();
  {
    float acc[R];
    float bv = b1[tid];
    #pragma unroll
    for (int rr = 0; rr < R; rr++) acc[rr] = bv;
    for (int d = 0; d < DIN; d++) {
      float wv = w1[d * 256 + tid];
      #pragma unroll
      for (int rr = 0; rr < R; rr++) acc[rr] += xs[rr][d] * wv;
    }
    #pragma unroll
    for (int rr = 0; rr < R; rr++) h1s[rr][tid] = fmaxf(acc[rr], 0.f);
  }
  __syncthreads();
  {
    float acc0[R], acc1[R];
    float bv0 = b2[tid], bv1 = b2[tid + 256];
    #pragma unroll
    for (int rr = 0; rr < R; rr++) { acc0[rr] = bv0; acc1[rr] = bv1; }
    for (int d = 0; d < 256; d++) {
      float w0 = w2[d * 512 + tid];
      float w1v = w2[d * 512 + tid + 256];
      #pragma unroll
      for (int rr = 0; rr < R; rr++) {
        float h = h1s[rr][d];
        acc0[rr] += h * w0;
        acc1[rr] += h * w1v;
      }
    }
    #pragma unroll
    for (int rr = 0; rr < R; rr++) {
      h2s[rr][tid] = fmaxf(acc0[rr], 0.f);
      h2s[rr][tid + 256] = fmaxf(acc1[rr], 0.f);
    }
  }
  __syncthreads();
  for (int rr = 0; rr < R; rr++) {
    float v0 = h2s[rr][tid], v1 = h2s[rr][tid + 256];
    float s = v0 + v1, q = v0 * v0 + v1 * v1;
    block_reduce2(s, q, scratch);
    float mean = s * (1.f / 512.f);
    float var = q * (1.f / 512.f) - mean * mean;
    float rs = rsqrtf(var + 1e-5f);
    size_t r = (size_t)(r0 + rr);
    hseqb[r * 512 + tid] = f2b((v0 - mean) * rs * g[tid] + be[tid]);
    hseqb[r * 512 + tid + 256] = f2b((v1 - mean) * rs * g[tid + 256] + be[tid + 256]);
  }
}

// ---------------------------------------------------------------------------
// K2 v2: one GRU step, MFMA bf16, XCD-swizzled + double-buffered LDS.
// 1-D grid of 208 blocks: all 13 m-blocks of one (dir,j-tile) pair land on
// the same XCD (bid%8 = XCD round-robin) so the pair's 393KB weight slice
// stays L2-resident across all 60 steps. Register prefetch of the next
// K-chunk overlaps global latency with MFMA; ONE barrier per K-iter.
// ---------------------------------------------------------------------------
__global__ __launch_bounds__(256) void k_gru_mfma(
    const ushort_t* __restrict__ hseqb, const ushort_t* __restrict__ wb,
    const float* __restrict__ bih_f, const float* __restrict__ bhh_f,
    const float* __restrict__ bih_b, const float* __restrict__ bhh_b,
    float* __restrict__ hf32, ushort_t* __restrict__ hbb, int t)
{
  // double-buffered LDS, row stride 40 elems (80B): 16B-aligned, 2-way alias (free)
  __shared__ __align__(16) ushort_t Xs[2][64][40];
  __shared__ __align__(16) ushort_t Hs[2][64][40];
  __shared__ __align__(16) ushort_t Ws[2][6][64][40];

  // XCD-aware decode: pair p = dir*8+jt; blocks of pair p have bid%8 == p%8.
  const int bid = blockIdx.x;            // 0..207
  const int xslot = bid & 7;
  const int ii = bid >> 3;               // 0..25
  const int pair = (ii < 13) ? xslot : (xslot + 8);
  const int mt = (ii < 13) ? ii : (ii - 13);
  const int dir = pair >> 3;
  const int jt = pair & 7;
  const int j0g = jt * 64;
  const int m0g = mt * 64;

  const ushort_t* __restrict__ wih = wb + (size_t)dir * 1572864;
  const ushort_t* __restrict__ whh = wih + 786432;
  const float* __restrict__ bih = dir ? bih_b : bih_f;
  const float* __restrict__ bhh = dir ? bhh_b : bhh_f;
  const int xt = dir ? (SS - 1 - t) : t;
  const size_t par0 = (size_t)(t & 1) * 819200 + (size_t)dir * 409600;
  const size_t par1 = (size_t)((t + 1) & 1) * 819200 + (size_t)dir * 409600;
  const float* __restrict__ hprevf = hf32 + par0;
  float* __restrict__ hnewf = hf32 + par1;
  const ushort_t* __restrict__ hprevb = hbb + par0;
  ushort_t* __restrict__ hnewb = hbb + par1;

  const int tid = threadIdx.x;

  // staging: row = tid>>2 (0..63), k-group = (tid&3)*8
  const int srow = tid >> 2;
  const int skg = (tid & 3) * 8;
  const int smg = m0g + srow;
  const bool mok = smg < BN;
  const int smg_c = mok ? smg : 0;   // masked rows read row 0 (valid mem, result masked later)

  const ushort_t* __restrict__ px = hseqb + ((size_t)smg_c * SS + xt) * 512 + skg;
  const ushort_t* __restrict__ ph = hprevb + (size_t)smg_c * 512 + skg;
  const ushort_t* pw[6];
  #pragma unroll
  for (int tt = 0; tt < 6; tt++) {
    const ushort_t* src = (tt < 3) ? wih : whh;
    int gate = (tt < 3) ? tt : tt - 3;
    int jglob = gate * 512 + j0g + srow;
    pw[tt] = src + (size_t)jglob * 512 + skg;
  }

  const int wid = tid >> 6;
  const int l = tid & 63;
  const int lr = l & 15;       // A row / B col / C col
  const int lg = l >> 4;       // k-group / C row-group
  const int mbase = (wid >> 1) * 32;
  const int nbase = (wid & 1) * 32;

  f32x4 accr[2][2] = {};
  f32x4 accz[2][2] = {};
  f32x4 accin[2][2] = {};
  f32x4 acchn[2][2] = {};

  // prologue: k0 = 0
  s16x8 rx = *reinterpret_cast<const s16x8*>(px);
  s16x8 rh = *reinterpret_cast<const s16x8*>(ph);
  s16x8 rw[6];
  #pragma unroll
  for (int tt = 0; tt < 6; tt++) rw[tt] = *reinterpret_cast<const s16x8*>(pw[tt]);
  *reinterpret_cast<s16x8*>(&Xs[0][srow][skg]) = rx;
  *reinterpret_cast<s16x8*>(&Hs[0][srow][skg]) = rh;
  #pragma unroll
  for (int tt = 0; tt < 6; tt++) *reinterpret_cast<s16x8*>(&Ws[0][tt][srow][skg]) = rw[tt];
  __syncthreads();

  for (int it = 0; it < 16; ++it) {
    const int cur = it & 1;
    if (it < 15) {
      const int k0 = (it + 1) * 32;
      rx = *reinterpret_cast<const s16x8*>(px + k0);
      rh = *reinterpret_cast<const s16x8*>(ph + k0);
      #pragma unroll
      for (int tt = 0; tt < 6; tt++) rw[tt] = *reinterpret_cast<const s16x8*>(pw[tt] + k0);
    }

    bf16x8 xA[2], hA[2];
    #pragma unroll
    for (int mi = 0; mi < 2; mi++) {
      xA[mi] = *reinterpret_cast<const bf16x8*>(&Xs[cur][mbase + mi * 16 + lr][lg * 8]);
      hA[mi] = *reinterpret_cast<const bf16x8*>(&Hs[cur][mbase + mi * 16 + lr][lg * 8]);
    }
    #pragma unroll
    for (int ni = 0; ni < 2; ni++) {
      const int wrow = nbase + ni * 16 + lr;
      bf16x8 bWr = *reinterpret_cast<const bf16x8*>(&Ws[cur][0][wrow][lg * 8]);
      bf16x8 bWz = *reinterpret_cast<const bf16x8*>(&Ws[cur][1][wrow][lg * 8]);
      bf16x8 bWn = *reinterpret_cast<const bf16x8*>(&Ws[cur][2][wrow][lg * 8]);
      bf16x8 bVr = *reinterpret_cast<const bf16x8*>(&Ws[cur][3][wrow][lg * 8]);
      bf16x8 bVz = *reinterpret_cast<const bf16x8*>(&Ws[cur][4][wrow][lg * 8]);
      bf16x8 bVn = *reinterpret_cast<const bf16x8*>(&Ws[cur][5][wrow][lg * 8]);
      #pragma unroll
      for (int mi = 0; mi < 2; mi++) {
        accr[mi][ni]  = __builtin_amdgcn_mfma_f32_16x16x32_bf16(xA[mi], bWr, accr[mi][ni], 0, 0, 0);
        accr[mi][ni]  = __builtin_amdgcn_mfma_f32_16x16x32_bf16(hA[mi], bVr, accr[mi][ni], 0, 0, 0);
        accz[mi][ni]  = __builtin_amdgcn_mfma_f32_16x16x32_bf16(xA[mi], bWz, accz[mi][ni], 0, 0, 0);
        accz[mi][ni]  = __builtin_amdgcn_mfma_f32_16x16x32_bf16(hA[mi], bVz, accz[mi][ni], 0, 0, 0);
        accin[mi][ni] = __builtin_amdgcn_mfma_f32_16x16x32_bf16(xA[mi], bWn, accin[mi][ni], 0, 0, 0);
        acchn[mi][ni] = __builtin_amdgcn_mfma_f32_16x16x32_bf16(hA[mi], bVn, acchn[mi][ni], 0, 0, 0);
      }
    }

    if (it < 15) {
      const int nxt = cur ^ 1;
      *reinterpret_cast<s16x8*>(&Xs[nxt][srow][skg]) = rx;
      *reinterpret_cast<s16x8*>(&Hs[nxt][srow][skg]) = rh;
      #pragma unroll
      for (int tt = 0; tt < 6; tt++) *reinterpret_cast<s16x8*>(&Ws[nxt][tt][srow][skg]) = rw[tt];
    }
    __syncthreads();
  }

  // epilogue: C frag mapping col = lane&15, row = 4*(lane>>4)+reg (m89-verified)
  #pragma unroll
  for (int mi = 0; mi < 2; mi++) {
    #pragma unroll
    for (int r = 0; r < 4; r++) {
      int m = m0g + mbase + mi * 16 + lg * 4 + r;
      if (m >= BN) continue;
      #pragma unroll
      for (int ni = 0; ni < 2; ni++) {
        int j = j0g + nbase + ni * 16 + lr;
        float sr = accr[mi][ni][r] + bih[j] + bhh[j];
        float sz = accz[mi][ni][r] + bih[512 + j] + bhh[512 + j];
        float rg = sig_fast(sr);
        float zg = sig_fast(sz);
        float ng = tanh_fast(accin[mi][ni][r] + bih[1024 + j] + rg * (acchn[mi][ni][r] + bhh[1024 + j]));
        float hp = hprevf[(size_t)m * 512 + j];
        float hvv = (1.f - zg) * ng + zg * hp;
        hnewf[(size_t)m * 512 + j] = hvv;
        hnewb[(size_t)m * 512 + j] = f2b(hvv);
      }
    }
  }
}

// ---------------------------------------------------------------------------
// K3: hn = LN(concat(hf, hb)) over 1024. grid 800, 256 threads.
// ---------------------------------------------------------------------------
__global__ __launch_bounds__(256) void k_ln_hn(
    const float* __restrict__ hf, const float* __restrict__ hb,
    const float* __restrict__ g, const float* __restrict__ be,
    float* __restrict__ hn)
{
  __shared__ float scratch[8];
  int row = blockIdx.x, tid = threadIdx.x;
  float v[4];
  float s = 0.f, q = 0.f;
  #pragma unroll
  for (int p = 0; p < 4; p++) {
    int c = p * 256 + tid;
    float val = (c < 512) ? hf[(size_t)row * 512 + c] : hb[(size_t)row * 512 + (c - 512)];
    v[p] = val; s += val; q += val * val;
  }
  block_reduce2(s, q, scratch);
  float mean = s * (1.f / 1024.f);
  float var = q * (1.f / 1024.f) - mean * mean;
  float rs = rsqrtf(var + 1e-5f);
  #pragma unroll
  for (int p = 0; p < 4; p++) {
    int c = p * 256 + tid;
    hn[(size_t)row * 1024 + c] = (v[p] - mean) * rs * g[c] + be[c];
  }
}

// ---------------------------------------------------------------------------
// Generic tiled SGEMM. C[m][n] = act(bias[n] + sum_k A[m][k]*B(k,n))
// ---------------------------------------------------------------------------
template<bool BT, int ACT>
__global__ __launch_bounds__(256) void k_sgemm(
    const float* __restrict__ A, const float* __restrict__ B,
    const float* __restrict__ bias, float* __restrict__ C,
    int M, int N, int K, int lda, int ldb, int ldc)
{
  __shared__ float As[16][68];
  __shared__ float Bs[16][68];
  int tid = threadIdx.x;
  int tx = tid & 15, ty = tid >> 4;
  int n0g = blockIdx.x * 64, m0g = blockIdx.y * 64;
  float acc[4][4] = {{0.f}};

  for (int k0 = 0; k0 < K; k0 += 16) {
    {
      int m = tid >> 2, kq = (tid & 3) * 4;
      int mg = m0g + m;
      float v[4] = {0.f, 0.f, 0.f, 0.f};
      if (mg < M) {
        float4 t4 = *reinterpret_cast<const float4*>(A + (size_t)mg * lda + k0 + kq);
        v[0] = t4.x; v[1] = t4.y; v[2] = t4.z; v[3] = t4.w;
      }
      #pragma unroll
      for (int i = 0; i < 4; i++) As[kq + i][m] = v[i];
    }
    if (BT) {
      int n = tid >> 2, kq = (tid & 3) * 4;
      int ng = n0g + n;
      float v[4] = {0.f, 0.f, 0.f, 0.f};
      if (ng < N) {
        float4 t4 = *reinterpret_cast<const float4*>(B + (size_t)ng * ldb + k0 + kq);
        v[0] = t4.x; v[1] = t4.y; v[2] = t4.z; v[3] = t4.w;
      }
      #pragma unroll
      for (int i = 0; i < 4; i++) Bs[kq + i][n] = v[i];
    } else {
      int k = tid >> 4, n0 = (tid & 15) * 4;
      int ng = n0g + n0;
      float v[4] = {0.f, 0.f, 0.f, 0.f};
      if (ng < N) {
        float4 t4 = *reinterpret_cast<const float4*>(B + (size_t)(k0 + k) * ldb + ng);
        v[0] = t4.x; v[1] = t4.y; v[2] = t4.z; v[3] = t4.w;
      }
      #pragma unroll
      for (int i = 0; i < 4; i++) Bs[k][n0 + i] = v[i];
    }
    __syncthreads();
    #pragma unroll
    for (int k = 0; k < 16; k++) {
      float4 a4 = *reinterpret_cast<const float4*>(&As[k][ty * 4]);
      float4 b4 = *reinterpret_cast<const float4*>(&Bs[k][tx * 4]);
      float a[4] = {a4.x, a4.y, a4.z, a4.w};
      float bb[4] = {b4.x, b4.y, b4.z, b4.w};
      #pragma unroll
      for (int i = 0; i < 4; i++)
        #pragma unroll
        for (int j = 0; j < 4; j++)
          acc[i][j] += a[i] * bb[j];
    }
    __syncthreads();
  }
  #pragma unroll
  for (int i = 0; i < 4; i++) {
    int mg = m0g + ty * 4 + i;
    if (mg >= M) continue;
    #pragma unroll
    for (int j = 0; j < 4; j++) {
      int ng = n0g + tx * 4 + j;
      if (ng >= N) continue;
      float v = acc[i][j] + (bias ? bias[ng] : 0.f);
      if (ACT == 1) v = fmaxf(v, 0.f);
      C[(size_t)mg * ldc + ng] = v;
    }
  }
}

// ---------------------------------------------------------------------------
// K4: per (b,h) attention scores + softmax. Writes sc[(b*8+h)*640 + i*25+j].
// ---------------------------------------------------------------------------
__global__ __launch_bounds__(256) void k_scores(const float* __restrict__ qkv,
                                                float* __restrict__ sc)
{
  int b = blockIdx.x, h = blockIdx.y;
  __shared__ float qs[25][128];
  __shared__ float ks[25][129];
  __shared__ float ps[25][26];
  int tid = threadIdx.x;
  for (int idx = tid; idx < 3200; idx += 256) {
    int i = idx >> 7, d = idx & 127;
    const float* base = qkv + (size_t)(b * 25 + i) * 2048 + h * 128 + d;
    qs[i][d] = base[0];
    ks[i][d] = base[1024];
  }
  __syncthreads();
  const float scale = 0.08838834764831845f;  // 1/sqrt(128)
  for (int e = tid; e < 625; e += 256) {
    int i = e / 25, j = e % 25;
    float s = 0.f;
    for (int d = 0; d < 128; d++) s += qs[i][d] * ks[j][d];
    ps[i][j] = s * scale;
  }
  __syncthreads();
  if (tid < 25) {
    float mx = -1e30f;
    for (int j = 0; j < 25; j++) mx = fmaxf(mx, ps[tid][j]);
    float s = 0.f;
    for (int j = 0; j < 25; j++) { float ev = expf(ps[tid][j] - mx); ps[tid][j] = ev; s += ev; }
    float inv = 1.f / s;
    for (int j = 0; j < 25; j++) ps[tid][j] *= inv;
  }
  __syncthreads();
  float* out = sc + (size_t)(b * 8 + h) * 640;
  for (int e = tid; e < 625; e += 256) out[e] = ps[e / 25][e % 25];
}

// ---------------------------------------------------------------------------
// K5: generic per-row LayerNorm. C = PER*256. dst[row*dstStride + dstOff + c]
// ---------------------------------------------------------------------------
template<int PER>
__global__ __launch_bounds__(256) void k_ln_rows(
    const float* __restrict__ src, float* __restrict__ dst,
    const float* __restrict__ g, const float* __restrict__ be,
    int dstStride, int dstOff)
{
  __shared__ float scratch[8];
  int row = blockIdx.x, tid = threadIdx.x;
  const int C = PER * 256;
  float v[PER];
  float s = 0.f, q = 0.f;
  #pragma unroll
  for (int p = 0; p < PER; p++) {
    v[p] = src[(size_t)row * C + p * 256 + tid];
    s += v[p]; q += v[p] * v[p];
  }
  block_reduce2(s, q, scratch);
  float mean = s / (float)C;
  float var = q / (float)C - mean * mean;
  float rs = rsqrtf(var + 1e-5f);
  #pragma unroll
  for (int p = 0; p < PER; p++) {
    int c = p * 256 + tid;
    dst[(size_t)row * dstStride + dstOff + c] = (v[p] - mean) * rs * g[c] + be[c];
  }
}

// broadcast te into Xcat cols [512,1024)
__global__ __launch_bounds__(256) void k_bcast_te(const float* __restrict__ te,
                                                  float* __restrict__ xcat)
{
  int row = blockIdx.x, tid = threadIdx.x;
  int n = row % 25;
  xcat[(size_t)row * 1280 + 512 + tid] = te[n * 512 + tid];
  xcat[(size_t)row * 1280 + 768 + tid] = te[n * 512 + 256 + tid];
}

// ---------------------------------------------------------------------------
// K6: adjacency build (single block)
// ---------------------------------------------------------------------------
__global__ __launch_bounds__(256) void k_adj(
    const float* __restrict__ sc, const float* __restrict__ te,
    const float* __restrict__ alpha_p, const float* __restrict__ dist,
    float* __restrict__ adj)
{
  __shared__ float als[625];
  __shared__ float ninv[25];
  __shared__ float scratch[8];
  __shared__ float mxs;
  int tid = threadIdx.x;

  for (int e = tid; e < 625; e += 256) {
    float s = 0.f;
    for (int gq = 0; gq < 256; gq++) s += sc[(size_t)gq * 640 + e];
    als[e] = s * (1.f / 256.f);
  }
  if (tid < 25) {
    float s = 0.f;
    const float* tp = te + tid * 512;
    for (int d = 0; d < 512; d++) s += tp[d] * tp[d];
    ninv[tid] = 1.f / fmaxf(sqrtf(s), 1e-8f);
  }
  __syncthreads();
  float alpha = alpha_p[0];
  for (int e = tid; e < 625; e += 256) {
    int i = e / 25, j = e % 25;
    float dt = 0.f;
    const float* ti = te + i * 512;
    const float* tj = te + j * 512;
    for (int d = 0; d < 512; d++) dt += ti[d] * tj[d];
    float emb = dt * ninv[i] * ninv[j];
    als[e] = (alpha * dist[e] + (1.f - alpha) * emb) * als[e];
  }
  __syncthreads();
  float lm = 0.f;
  for (int e = tid; e < 625; e += 256) {
    float a = fmaxf(als[e], 0.f);
    lm = fmaxf(lm, powf(a, 2.5f));
  }
  #pragma unroll
  for (int off = 32; off > 0; off >>= 1) lm = fmaxf(lm, __shfl_down(lm, off));
  int w = tid >> 6;
  if ((tid & 63) == 0) scratch[w] = lm;
  __syncthreads();
  if (tid == 0) {
    float m2 = scratch[0];
    for (int i = 1; i < 4; i++) m2 = fmaxf(m2, scratch[i]);
    mxs = m2;
  }
  __syncthreads();
  float mx = mxs;
  for (int e = tid; e < 625; e += 256) {
    float a = als[e];
    float m = powf(fmaxf(a, 0.f), 2.5f) / mx;
    adj[e] = (m >= 0.08f) ? a : 0.f;
  }
}

// ---------------------------------------------------------------------------
// K7: GCN adjacency mix
// ---------------------------------------------------------------------------
template<int RESID, int LNORM>
__global__ __launch_bounds__(256) void k_mix(
    const float* __restrict__ adj, const float* __restrict__ tmp,
    const float* __restrict__ bias, const float* __restrict__ resid,
    const float* __restrict__ g, const float* __restrict__ be,
    float* __restrict__ out)
{
  __shared__ float adjs[25];
  __shared__ float scratch[8];
  int row = blockIdx.x;
  int b = row / 25, i = row % 25;
  int f = threadIdx.x;
  if (f < 25) adjs[f] = adj[f * 25 + i];
  __syncthreads();
  float acc = bias[f];
  const float* tp = tmp + (size_t)b * 25 * 256 + f;
  #pragma unroll 5
  for (int j = 0; j < 25; j++) acc += adjs[j] * tp[(size_t)j * 256];
  if (RESID) acc += resid[(size_t)row * 256 + f];
  float v = acc;
  if (LNORM) {
    float s = v, q = v * v;
    block_reduce2(s, q, scratch);
    float mean = s * (1.f / 256.f);
    float var = q * (1.f / 256.f) - mean * mean;
    v = (v - mean) * rsqrtf(var + 1e-5f) * g[f] + be[f];
  }
  out[(size_t)row * 256 + f] = fmaxf(v, 0.f);
}

// ---------------------------------------------------------------------------
// launch
// ---------------------------------------------------------------------------
extern "C" void kernel_launch(void* const* d_in, const int* in_sizes, int n_in,
                              void* d_out, int out_size, void* d_ws, size_t ws_size,
                              hipStream_t stream)
{
  (void)in_sizes; (void)n_in; (void)out_size; (void)ws_size;

  const float* x         = (const float*)d_in[0];
  const float* seq1_w1   = (const float*)d_in[1];
  const float* seq1_b1   = (const float*)d_in[2];
  const float* seq1_w2   = (const float*)d_in[3];
  const float* seq1_b2   = (const float*)d_in[4];
  const float* ln2_g     = (const float*)d_in[5];
  const float* ln2_b     = (const float*)d_in[6];
  const float* gru_wih_f = (const float*)d_in[7];
  const float* gru_whh_f = (const float*)d_in[8];
  const float* gru_bih_f = (const float*)d_in[9];
  const float* gru_bhh_f = (const float*)d_in[10];
  const float* gru_wih_b = (const float*)d_in[11];
  const float* gru_whh_b = (const float*)d_in[12];
  const float* gru_bih_b = (const float*)d_in[13];
  const float* gru_bhh_b = (const float*)d_in[14];
  const float* ln_g      = (const float*)d_in[15];
  const float* ln_b      = (const float*)d_in[16];
  const float* attn_in_w = (const float*)d_in[17];
  const float* attn_in_b = (const float*)d_in[18];
  const float* fc_ta_w   = (const float*)d_in[19];
  const float* fc_ta_b   = (const float*)d_in[20];
  const float* ln3_g     = (const float*)d_in[21];
  const float* ln3_b     = (const float*)d_in[22];
  const float* sem_embs  = (const float*)d_in[23];
  const float* sem_w     = (const float*)d_in[24];
  const float* sem_b     = (const float*)d_in[25];
  const float* lnsem_g   = (const float*)d_in[26];
  const float* lnsem_b   = (const float*)d_in[27];
  const float* att_alpha = (const float*)d_in[28];
  const float* dist_adj  = (const float*)d_in[29];
  const float* gcn_w0    = (const float*)d_in[30];
  const float* gcn_b0    = (const float*)d_in[31];
  const float* gcn_w1    = (const float*)d_in[32];
  const float* gcn_b1    = (const float*)d_in[33];
  const float* gcn_w2    = (const float*)d_in[34];
  const float* gcn_b2    = (const float*)d_in[35];
  const float* gln1_g    = (const float*)d_in[36];
  const float* gln1_b    = (const float*)d_in[37];
  const float* gln2_g    = (const float*)d_in[38];
  const float* gln2_b    = (const float*)d_in[39];
  const float* enc_ln_g  = (const float*)d_in[40];
  const float* enc_ln_b  = (const float*)d_in[41];
  const float* fc_w      = (const float*)d_in[42];
  const float* fc_b      = (const float*)d_in[43];

  float* w = (float*)d_ws;
  ushort_t* hseqb = (ushort_t*)(w + O_HSEQB);
  ushort_t* wb    = (ushort_t*)(w + O_WB);
  float* hf32 = w + O_HF32;
  ushort_t* hbb = (ushort_t*)(w + O_HBB);
  float* hn   = w + O_HN;
  float* qkv  = w + O_QKV;
  float* sc   = w + O_SC;
  float* adjw = w + O_ADJ;
  float* wr   = w + O_WR;
  float* tep  = w + O_TEP;
  float* te   = w + O_TE;
  float* xcat = w + O_XCAT;
  float* gtmp = w + O_GTMP;
  float* xg0  = w + O_XG0;
  float* xg1  = w + O_XG1;
  float* xg2  = w + O_XG2;

  // zero h0 (parity-0 block holds both directions contiguously)
  hipMemsetAsync(hf32, 0, (size_t)819200 * sizeof(float), stream);
  hipMemsetAsync(hbb, 0, (size_t)819200 * sizeof(ushort_t), stream);

  // weights -> bf16
  k_cvt_w<<<3072, 256, 0, stream>>>(gru_wih_f, gru_whh_f, gru_wih_b, gru_whh_b, wb);

  // input MLP + LN (bf16 out)
  k_mlp<<<48000 / 4, 256, 0, stream>>>(x, seq1_w1, seq1_b1, seq1_w2, seq1_b2,
                                       ln2_g, ln2_b, hseqb);

  // bidirectional GRU, 60 steps (MFMA, XCD-swizzled 1-D grid)
  for (int t = 0; t < SS; t++) {
    k_gru_mfma<<<208, 256, 0, stream>>>(
        hseqb, wb, gru_bih_f, gru_bhh_f, gru_bih_b, gru_bhh_b, hf32, hbb, t);
  }

  // hn = LN(concat(hf, hb)); final hidden sits in parity 0
  k_ln_hn<<<800, 256, 0, stream>>>(hf32, hf32 + 409600, ln_g, ln_b, hn);

  // q,k projection (skip v: unused). N=2048, ldc=2048.
  k_sgemm<true, 0><<<dim3(32, 13), 256, 0, stream>>>(
      hn, attn_in_w, attn_in_b, qkv, 800, 2048, 1024, 1024, 1024, 2048);

  // per (b,h) softmax attention
  k_scores<<<dim3(32, 8), 256, 0, stream>>>(qkv, sc);

  // semantic embedding projection + LN
  k_sgemm<false, 0><<<dim3(8, 1), 256, 0, stream>>>(
      sem_embs, sem_w, sem_b, tep, 25, 512, 768, 768, 512, 512);
  k_ln_rows<2><<<25, 256, 0, stream>>>(tep, te, lnsem_g, lnsem_b, 512, 0);

  // fc_ta + LN3 -> Xcat[:, 0:512]
  k_sgemm<false, 1><<<dim3(8, 13), 256, 0, stream>>>(
      hn, fc_ta_w, fc_ta_b, wr, 800, 512, 1024, 1024, 512, 512);
  k_ln_rows<2><<<800, 256, 0, stream>>>(wr, xcat, ln3_g, ln3_b, 1280, 0);
  k_bcast_te<<<800, 256, 0, stream>>>(te, xcat);

  // adjacency
  k_adj<<<1, 256, 0, stream>>>(sc, te, att_alpha, dist_adj, adjw);

  // GCN layer 0
  k_sgemm<false, 0><<<dim3(4, 13), 256, 0, stream>>>(
      xcat, gcn_w0, nullptr, gtmp, 800, 256, 1024, 1280, 256, 256);
  k_mix<0, 0><<<800, 256, 0, stream>>>(adjw, gtmp, gcn_b0, nullptr, nullptr, nullptr, xg0);
  // GCN layer 1
  k_sgemm<false, 0><<<dim3(4, 13), 256, 0, stream>>>(
      xg0, gcn_w1, nullptr, gtmp, 800, 256, 256, 256, 256, 256);
  k_mix<1, 1><<<800, 256, 0, stream>>>(adjw, gtmp, gcn_b1, xg0, gln1_g, gln1_b, xg1);
  // GCN layer 2
  k_sgemm<false, 0><<<dim3(4, 13), 256, 0, stream>>>(
      xg1, gcn_w2, nullptr, gtmp, 800, 256, 256, 256, 256, 256);
  k_mix<1, 1><<<800, 256, 0, stream>>>(adjw, gtmp, gcn_b2, xg1, gln2_g, gln2_b, xg2);

  // encoder LN -> Xcat[:, 1024:1280]
  k_ln_rows<1><<<800, 256, 0, stream>>>(xg2, xcat, enc_ln_g, enc_ln_b, 1280, 1024);

  // final fc + relu -> d_out
  k_sgemm<false, 1><<<dim3(8, 13), 256, 0, stream>>>(
      xcat, fc_w, fc_b, (float*)d_out, 800, 512, 1280, 1280, 512, 512);
}

// Round 4
// 1736.863 us; speedup vs baseline: 7.1762x; 1.2781x over previous
//
#include <hip/hip_runtime.h>
#include <hip/hip_bf16.h>
#include <math.h>

// ---------------------------------------------------------------------------
// Problem constants
// ---------------------------------------------------------------------------
#define BB 32
#define SS 60
#define NN_ 25
#define DIN 100
#define BN 800           // B*N
#define GRU_H 512
#define FDIM 1024        // TEMB+SEMB
#define CH 256
#define OUTD 512

typedef unsigned short ushort_t;
typedef float f32x4 __attribute__((ext_vector_type(4)));
typedef __bf16 bf16x8 __attribute__((ext_vector_type(8)));
typedef short s16x8 __attribute__((ext_vector_type(8)));

// workspace float offsets
static const size_t O_HSEQB = 0;          // bf16 48000*512
static const size_t O_WB    = 12288000;   // bf16 GRU weights
static const size_t O_HF32  = 13860864;
static const size_t O_HBB   = 15499264;
static const size_t O_HN    = 16318464;
static const size_t O_QKV   = 17137664;
static const size_t O_SC    = 18776064;
static const size_t O_ADJ   = 18939904;
static const size_t O_WR    = 18940544;
static const size_t O_TEP   = 19350144;
static const size_t O_TE    = 19362944;
static const size_t O_XCAT  = 19375744;
static const size_t O_GTMP  = 20399744;
static const size_t O_XG0   = 20604544;
static const size_t O_XG1   = 20809344;
static const size_t O_XG2   = 21014144;
// bf16 weight buffers (pre-transposed to [N][K])
static const size_t O_W1TB  = 21218944;   // 256x128
static const size_t O_W2TB  = 21235328;   // 512x256
static const size_t O_AWB   = 21300864;   // 2048x1024
static const size_t O_FTWB  = 22349440;   // 512x1024
static const size_t O_SMWB  = 22611584;   // 512x768
static const size_t O_G0WB  = 22808192;   // 256x1024
static const size_t O_G1WB  = 22939264;   // 256x256
static const size_t O_G2WB  = 22972032;   // 256x256
static const size_t O_FCWB  = 23004800;   // 512x1280
// total 23,332,480 floats = 93.3 MB

__device__ __forceinline__ ushort_t f2b(float v)
{
  __hip_bfloat16 b = __float2bfloat16(v);
  return *reinterpret_cast<ushort_t*>(&b);
}

__device__ __forceinline__ float sig_fast(float v)
{
  return 1.f / (1.f + __expf(-v));
}
__device__ __forceinline__ float tanh_fast(float v)
{
  return 1.f - 2.f / (1.f + __expf(2.f * v));
}

__device__ __forceinline__ void block_reduce2(float& s, float& q, float* scratch)
{
  __syncthreads();
  #pragma unroll
  for (int off = 32; off > 0; off >>= 1) {
    s += __shfl_down(s, off);
    q += __shfl_down(q, off);
  }
  int tid = threadIdx.x;
  int w = tid >> 6;
  if ((tid & 63) == 0) { scratch[w * 2] = s; scratch[w * 2 + 1] = q; }
  __syncthreads();
  if (tid == 0) {
    float ss = 0.f, qq = 0.f;
    int nw = blockDim.x >> 6;
    for (int i = 0; i < nw; i++) { ss += scratch[i * 2]; qq += scratch[i * 2 + 1]; }
    scratch[0] = ss; scratch[1] = qq;
  }
  __syncthreads();
  s = scratch[0]; q = scratch[1];
}

// ---------------------------------------------------------------------------
// converts
// ---------------------------------------------------------------------------
__global__ __launch_bounds__(256) void k_cvt_w(
    const float* __restrict__ wih_f, const float* __restrict__ whh_f,
    const float* __restrict__ wih_b, const float* __restrict__ whh_b,
    ushort_t* __restrict__ wb)
{
  int i = blockIdx.x * 256 + threadIdx.x;
  wb[i]           = f2b(wih_f[i]);
  wb[786432 + i]  = f2b(whh_f[i]);
  wb[1572864 + i] = f2b(wih_b[i]);
  wb[2359296 + i] = f2b(whh_b[i]);
}

// plain fp32 -> bf16 (same layout)
__global__ __launch_bounds__(256) void k_cvt_plain(
    const float* __restrict__ src, ushort_t* __restrict__ dst, int count)
{
  int i = blockIdx.x * 256 + threadIdx.x;
  if (i < count) dst[i] = f2b(src[i]);
}

// transpose [K][N] fp32 -> [N][KP] bf16 (pad K..KP with zeros)
__global__ __launch_bounds__(256) void k_cvt_t(
    const float* __restrict__ src, ushort_t* __restrict__ dst,
    int K, int N, int KP)
{
  __shared__ float tile[32][33];
  int tx = threadIdx.x & 31, ty = threadIdx.x >> 5;
  int n0 = blockIdx.x * 32, k0 = blockIdx.y * 32;
  #pragma unroll
  for (int i = 0; i < 4; i++) {
    int k = k0 + ty + i * 8, n = n0 + tx;
    tile[ty + i * 8][tx] = (k < K && n < N) ? src[(size_t)k * N + n] : 0.f;
  }
  __syncthreads();
  #pragma unroll
  for (int i = 0; i < 4; i++) {
    int n = n0 + ty + i * 8, k = k0 + tx;
    if (n < N && k < KP) dst[(size_t)n * KP + k] = f2b(tile[tx][ty + i * 8]);
  }
}

// ---------------------------------------------------------------------------
// K1: fused MLP (100->256 relu -> 512 relu) + LN(512), all-MFMA, bf16 out.
// 750 blocks x 64 rows. 4 waves, each wave owns 16 full rows.
// ---------------------------------------------------------------------------
__global__ __launch_bounds__(256, 1) void k_mlp_fused(
    const float* __restrict__ x,
    const ushort_t* __restrict__ w1tb,   // [256][128]
    const float* __restrict__ b1,
    const ushort_t* __restrict__ w2tb,   // [512][256]
    const float* __restrict__ b2,
    const float* __restrict__ g, const float* __restrict__ be,
    ushort_t* __restrict__ hseqb)
{
  __shared__ __align__(16) ushort_t xb[64][136];
  __shared__ __align__(16) ushort_t Bl[512][40];
  __shared__ __align__(16) ushort_t h1[64][264];
  const int tid = threadIdx.x;
  const int r0 = blockIdx.x * 64;

  // stage x -> bf16 LDS, K padded to 128
  {
    int rr = tid >> 2;
    int d0 = (tid & 3) * 32;
    int r = r0 + rr;
    int bn = r / SS, s = r % SS;
    int b = bn / NN_, n = bn % NN_;
    const float* xp = x + (((size_t)b * SS + s) * NN_ + n) * DIN;
    ushort_t tmp[32];
    #pragma unroll
    for (int i = 0; i < 32; i++) {
      int d = d0 + i;
      tmp[i] = (d < DIN) ? f2b(xp[d]) : (ushort_t)0;
    }
    #pragma unroll
    for (int i = 0; i < 4; i++)
      *reinterpret_cast<s16x8*>(&xb[rr][d0 + i * 8]) = *reinterpret_cast<s16x8*>(&tmp[i * 8]);
  }
  const int wid = tid >> 6, l = tid & 63, lr = l & 15, lg = l >> 4;
  const int srow = tid >> 2, skg = (tid & 3) * 8;

  // ---- layer 1: 64x256, K=128 ----
  f32x4 acc1[16] = {};
  for (int kc = 0; kc < 4; kc++) {
    __syncthreads();   // xb ready (kc=0) / Bl reads done (kc>0)
    #pragma unroll
    for (int i = 0; i < 4; i++) {
      int row = srow + i * 64;
      *reinterpret_cast<s16x8*>(&Bl[row][skg]) =
          *reinterpret_cast<const s16x8*>(w1tb + (size_t)row * 128 + kc * 32 + skg);
    }
    __syncthreads();
    bf16x8 aF = *reinterpret_cast<const bf16x8*>(&xb[wid * 16 + lr][kc * 32 + lg * 8]);
    #pragma unroll
    for (int ni = 0; ni < 16; ni++) {
      bf16x8 bF = *reinterpret_cast<const bf16x8*>(&Bl[ni * 16 + lr][lg * 8]);
      acc1[ni] = __builtin_amdgcn_mfma_f32_16x16x32_bf16(aF, bF, acc1[ni], 0, 0, 0);
    }
  }
  // relu -> h1 bf16 (each wave writes its own 16 rows)
  #pragma unroll
  for (int ni = 0; ni < 16; ni++) {
    #pragma unroll
    for (int r = 0; r < 4; r++) {
      int row = wid * 16 + lg * 4 + r;
      int col = ni * 16 + lr;
      h1[row][col] = f2b(fmaxf(acc1[ni][r] + b1[col], 0.f));
    }
  }

  // ---- layer 2: 64x512, K=256 ----
  f32x4 acc2[32] = {};
  for (int kc = 0; kc < 8; kc++) {
    __syncthreads();   // h1 ready (kc=0) / Bl reads done
    #pragma unroll
    for (int i = 0; i < 8; i++) {
      int row = srow + i * 64;
      *reinterpret_cast<s16x8*>(&Bl[row][skg]) =
          *reinterpret_cast<const s16x8*>(w2tb + (size_t)row * 256 + kc * 32 + skg);
    }
    __syncthreads();
    bf16x8 aF = *reinterpret_cast<const bf16x8*>(&h1[wid * 16 + lr][kc * 32 + lg * 8]);
    #pragma unroll
    for (int ni = 0; ni < 32; ni++) {
      bf16x8 bF = *reinterpret_cast<const bf16x8*>(&Bl[ni * 16 + lr][lg * 8]);
      acc2[ni] = __builtin_amdgcn_mfma_f32_16x16x32_bf16(aF, bF, acc2[ni], 0, 0, 0);
    }
  }

  // ---- bias + relu + in-register LN over 512 (reduce across lr group) ----
  float su[4] = {0.f, 0.f, 0.f, 0.f}, sq[4] = {0.f, 0.f, 0.f, 0.f};
  #pragma unroll
  for (int ni = 0; ni < 32; ni++) {
    float bb = b2[ni * 16 + lr];
    #pragma unroll
    for (int r = 0; r < 4; r++) {
      float v = fmaxf(acc2[ni][r] + bb, 0.f);
      acc2[ni][r] = v;
      su[r] += v; sq[r] += v * v;
    }
  }
  #pragma unroll
  for (int off = 1; off < 16; off <<= 1) {
    #pragma unroll
    for (int r = 0; r < 4; r++) {
      su[r] += __shfl_xor(su[r], off);
      sq[r] += __shfl_xor(sq[r], off);
    }
  }
  #pragma unroll
  for (int r = 0; r < 4; r++) {
    float mean = su[r] * (1.f / 512.f);
    float var = sq[r] * (1.f / 512.f) - mean * mean;
    float rs = rsqrtf(var + 1e-5f);
    int rowg = r0 + wid * 16 + lg * 4 + r;
    ushort_t* outp = hseqb + (size_t)rowg * 512;
    #pragma unroll
    for (int ni = 0; ni < 32; ni++) {
      int col = ni * 16 + lr;
      outp[col] = f2b((acc2[ni][r] - mean) * rs * g[col] + be[col]);
    }
  }
}

// ---------------------------------------------------------------------------
// K2: one GRU step, MFMA bf16, XCD-swizzled + double-buffered LDS (R3).
// ---------------------------------------------------------------------------
__global__ __launch_bounds__(256) void k_gru_mfma(
    const ushort_t* __restrict__ hseqb, const ushort_t* __restrict__ wb,
    const float* __restrict__ bih_f, const float* __restrict__ bhh_f,
    const float* __restrict__ bih_b, const float* __restrict__ bhh_b,
    float* __restrict__ hf32, ushort_t* __restrict__ hbb, int t)
{
  __shared__ __align__(16) ushort_t Xs[2][64][40];
  __shared__ __align__(16) ushort_t Hs[2][64][40];
  __shared__ __align__(16) ushort_t Ws[2][6][64][40];

  const int bid = blockIdx.x;            // 0..207
  const int xslot = bid & 7;
  const int ii = bid >> 3;
  const int pair = (ii < 13) ? xslot : (xslot + 8);
  const int mt = (ii < 13) ? ii : (ii - 13);
  const int dir = pair >> 3;
  const int jt = pair & 7;
  const int j0g = jt * 64;
  const int m0g = mt * 64;

  const ushort_t* __restrict__ wih = wb + (size_t)dir * 1572864;
  const ushort_t* __restrict__ whh = wih + 786432;
  const float* __restrict__ bih = dir ? bih_b : bih_f;
  const float* __restrict__ bhh = dir ? bhh_b : bhh_f;
  const int xt = dir ? (SS - 1 - t) : t;
  const size_t par0 = (size_t)(t & 1) * 819200 + (size_t)dir * 409600;
  const size_t par1 = (size_t)((t + 1) & 1) * 819200 + (size_t)dir * 409600;
  const float* __restrict__ hprevf = hf32 + par0;
  float* __restrict__ hnewf = hf32 + par1;
  const ushort_t* __restrict__ hprevb = hbb + par0;
  ushort_t* __restrict__ hnewb = hbb + par1;

  const int tid = threadIdx.x;
  const int srow = tid >> 2;
  const int skg = (tid & 3) * 8;
  const int smg = m0g + srow;
  const int smg_c = (smg < BN) ? smg : 0;

  const ushort_t* __restrict__ px = hseqb + ((size_t)smg_c * SS + xt) * 512 + skg;
  const ushort_t* __restrict__ ph = hprevb + (size_t)smg_c * 512 + skg;
  const ushort_t* pw[6];
  #pragma unroll
  for (int tt = 0; tt < 6; tt++) {
    const ushort_t* src = (tt < 3) ? wih : whh;
    int gate = (tt < 3) ? tt : tt - 3;
    int jglob = gate * 512 + j0g + srow;
    pw[tt] = src + (size_t)jglob * 512 + skg;
  }

  const int wid = tid >> 6;
  const int l = tid & 63;
  const int lr = l & 15;
  const int lg = l >> 4;
  const int mbase = (wid >> 1) * 32;
  const int nbase = (wid & 1) * 32;

  f32x4 accr[2][2] = {};
  f32x4 accz[2][2] = {};
  f32x4 accin[2][2] = {};
  f32x4 acchn[2][2] = {};

  s16x8 rx = *reinterpret_cast<const s16x8*>(px);
  s16x8 rh = *reinterpret_cast<const s16x8*>(ph);
  s16x8 rw[6];
  #pragma unroll
  for (int tt = 0; tt < 6; tt++) rw[tt] = *reinterpret_cast<const s16x8*>(pw[tt]);
  *reinterpret_cast<s16x8*>(&Xs[0][srow][skg]) = rx;
  *reinterpret_cast<s16x8*>(&Hs[0][srow][skg]) = rh;
  #pragma unroll
  for (int tt = 0; tt < 6; tt++) *reinterpret_cast<s16x8*>(&Ws[0][tt][srow][skg]) = rw[tt];
  __syncthreads();

  for (int it = 0; it < 16; ++it) {
    const int cur = it & 1;
    if (it < 15) {
      const int k0 = (it + 1) * 32;
      rx = *reinterpret_cast<const s16x8*>(px + k0);
      rh = *reinterpret_cast<const s16x8*>(ph + k0);
      #pragma unroll
      for (int tt = 0; tt < 6; tt++) rw[tt] = *reinterpret_cast<const s16x8*>(pw[tt] + k0);
    }

    bf16x8 xA[2], hA[2];
    #pragma unroll
    for (int mi = 0; mi < 2; mi++) {
      xA[mi] = *reinterpret_cast<const bf16x8*>(&Xs[cur][mbase + mi * 16 + lr][lg * 8]);
      hA[mi] = *reinterpret_cast<const bf16x8*>(&Hs[cur][mbase + mi * 16 + lr][lg * 8]);
    }
    #pragma unroll
    for (int ni = 0; ni < 2; ni++) {
      const int wrow = nbase + ni * 16 + lr;
      bf16x8 bWr = *reinterpret_cast<const bf16x8*>(&Ws[cur][0][wrow][lg * 8]);
      bf16x8 bWz = *reinterpret_cast<const bf16x8*>(&Ws[cur][1][wrow][lg * 8]);
      bf16x8 bWn = *reinterpret_cast<const bf16x8*>(&Ws[cur][2][wrow][lg * 8]);
      bf16x8 bVr = *reinterpret_cast<const bf16x8*>(&Ws[cur][3][wrow][lg * 8]);
      bf16x8 bVz = *reinterpret_cast<const bf16x8*>(&Ws[cur][4][wrow][lg * 8]);
      bf16x8 bVn = *reinterpret_cast<const bf16x8*>(&Ws[cur][5][wrow][lg * 8]);
      #pragma unroll
      for (int mi = 0; mi < 2; mi++) {
        accr[mi][ni]  = __builtin_amdgcn_mfma_f32_16x16x32_bf16(xA[mi], bWr, accr[mi][ni], 0, 0, 0);
        accr[mi][ni]  = __builtin_amdgcn_mfma_f32_16x16x32_bf16(hA[mi], bVr, accr[mi][ni], 0, 0, 0);
        accz[mi][ni]  = __builtin_amdgcn_mfma_f32_16x16x32_bf16(xA[mi], bWz, accz[mi][ni], 0, 0, 0);
        accz[mi][ni]  = __builtin_amdgcn_mfma_f32_16x16x32_bf16(hA[mi], bVz, accz[mi][ni], 0, 0, 0);
        accin[mi][ni] = __builtin_amdgcn_mfma_f32_16x16x32_bf16(xA[mi], bWn, accin[mi][ni], 0, 0, 0);
        acchn[mi][ni] = __builtin_amdgcn_mfma_f32_16x16x32_bf16(hA[mi], bVn, acchn[mi][ni], 0, 0, 0);
      }
    }

    if (it < 15) {
      const int nxt = cur ^ 1;
      *reinterpret_cast<s16x8*>(&Xs[nxt][srow][skg]) = rx;
      *reinterpret_cast<s16x8*>(&Hs[nxt][srow][skg]) = rh;
      #pragma unroll
      for (int tt = 0; tt < 6; tt++) *reinterpret_cast<s16x8*>(&Ws[nxt][tt][srow][skg]) = rw[tt];
    }
    __syncthreads();
  }

  #pragma unroll
  for (int mi = 0; mi < 2; mi++) {
    #pragma unroll
    for (int r = 0; r < 4; r++) {
      int m = m0g + mbase + mi * 16 + lg * 4 + r;
      if (m >= BN) continue;
      #pragma unroll
      for (int ni = 0; ni < 2; ni++) {
        int j = j0g + nbase + ni * 16 + lr;
        float sr = accr[mi][ni][r] + bih[j] + bhh[j];
        float sz = accz[mi][ni][r] + bih[512 + j] + bhh[512 + j];
        float rg = sig_fast(sr);
        float zg = sig_fast(sz);
        float ng = tanh_fast(accin[mi][ni][r] + bih[1024 + j] + rg * (acchn[mi][ni][r] + bhh[1024 + j]));
        float hp = hprevf[(size_t)m * 512 + j];
        float hvv = (1.f - zg) * ng + zg * hp;
        hnewf[(size_t)m * 512 + j] = hvv;
        hnewb[(size_t)m * 512 + j] = f2b(hvv);
      }
    }
  }
}

// ---------------------------------------------------------------------------
// K3: hn = LN(concat(hf, hb)) over 1024.
// ---------------------------------------------------------------------------
__global__ __launch_bounds__(256) void k_ln_hn(
    const float* __restrict__ hf, const float* __restrict__ hb,
    const float* __restrict__ g, const float* __restrict__ be,
    float* __restrict__ hn)
{
  __shared__ float scratch[8];
  int row = blockIdx.x, tid = threadIdx.x;
  float v[4];
  float s = 0.f, q = 0.f;
  #pragma unroll
  for (int p = 0; p < 4; p++) {
    int c = p * 256 + tid;
    float val = (c < 512) ? hf[(size_t)row * 512 + c] : hb[(size_t)row * 512 + (c - 512)];
    v[p] = val; s += val; q += val * val;
  }
  block_reduce2(s, q, scratch);
  float mean = s * (1.f / 1024.f);
  float var = q * (1.f / 1024.f) - mean * mean;
  float rs = rsqrtf(var + 1e-5f);
  #pragma unroll
  for (int p = 0; p < 4; p++) {
    int c = p * 256 + tid;
    hn[(size_t)row * 1024 + c] = (v[p] - mean) * rs * g[c] + be[c];
  }
}

// ---------------------------------------------------------------------------
// bf16 MFMA GEMM: C = act(bias + A(fp32,cvt) @ B(bf16,[N][K])^T)
// 64x64 tile, 4 waves 2x2 of 32x32, K-chunk 32. K % 32 == 0.
// ---------------------------------------------------------------------------
template<int ACT>
__global__ __launch_bounds__(256) void k_bgemm(
    const float* __restrict__ A, const ushort_t* __restrict__ B,
    const float* __restrict__ bias, float* __restrict__ C,
    int M, int N, int K, int lda, int ldc)
{
  __shared__ __align__(16) ushort_t Al[64][40];
  __shared__ __align__(16) ushort_t Bl[64][40];
  const int tid = threadIdx.x;
  const int n0g = blockIdx.x * 64, m0g = blockIdx.y * 64;
  const int srow = tid >> 2, skg = (tid & 3) * 8;
  const int smg = (m0g + srow < M) ? (m0g + srow) : (M - 1);
  const int sng = (n0g + srow < N) ? (n0g + srow) : (N - 1);
  const float* pa = A + (size_t)smg * lda + skg;
  const ushort_t* pb = B + (size_t)sng * K + skg;
  const int wid = tid >> 6, l = tid & 63, lr = l & 15, lg = l >> 4;
  const int mbase = (wid >> 1) * 32, nbase = (wid & 1) * 32;
  f32x4 acc[2][2] = {};

  for (int k0 = 0; k0 < K; k0 += 32) {
    float4 a0 = *reinterpret_cast<const float4*>(pa + k0);
    float4 a1 = *reinterpret_cast<const float4*>(pa + k0 + 4);
    s16x8 bv = *reinterpret_cast<const s16x8*>(pb + k0);
    ushort_t tmp[8] = {f2b(a0.x), f2b(a0.y), f2b(a0.z), f2b(a0.w),
                       f2b(a1.x), f2b(a1.y), f2b(a1.z), f2b(a1.w)};
    *reinterpret_cast<s16x8*>(&Al[srow][skg]) = *reinterpret_cast<s16x8*>(tmp);
    *reinterpret_cast<s16x8*>(&Bl[srow][skg]) = bv;
    __syncthreads();
    bf16x8 aF[2], bF[2];
    #pragma unroll
    for (int mi = 0; mi < 2; mi++)
      aF[mi] = *reinterpret_cast<const bf16x8*>(&Al[mbase + mi * 16 + lr][lg * 8]);
    #pragma unroll
    for (int ni = 0; ni < 2; ni++)
      bF[ni] = *reinterpret_cast<const bf16x8*>(&Bl[nbase + ni * 16 + lr][lg * 8]);
    #pragma unroll
    for (int mi = 0; mi < 2; mi++)
      #pragma unroll
      for (int ni = 0; ni < 2; ni++)
        acc[mi][ni] = __builtin_amdgcn_mfma_f32_16x16x32_bf16(aF[mi], bF[ni], acc[mi][ni], 0, 0, 0);
    __syncthreads();
  }
  #pragma unroll
  for (int mi = 0; mi < 2; mi++) {
    #pragma unroll
    for (int r = 0; r < 4; r++) {
      int mg = m0g + mbase + mi * 16 + lg * 4 + r;
      if (mg >= M) continue;
      #pragma unroll
      for (int ni = 0; ni < 2; ni++) {
        int ng = n0g + nbase + ni * 16 + lr;
        if (ng >= N) continue;
        float v = acc[mi][ni][r] + (bias ? bias[ng] : 0.f);
        if (ACT == 1) v = fmaxf(v, 0.f);
        C[(size_t)mg * ldc + ng] = v;
      }
    }
  }
}

// ---------------------------------------------------------------------------
// K4: per (b,h) attention scores + softmax.
// ---------------------------------------------------------------------------
__global__ __launch_bounds__(256) void k_scores(const float* __restrict__ qkv,
                                                float* __restrict__ sc)
{
  int b = blockIdx.x, h = blockIdx.y;
  __shared__ float qs[25][128];
  __shared__ float ks[25][129];
  __shared__ float ps[25][26];
  int tid = threadIdx.x;
  for (int idx = tid; idx < 3200; idx += 256) {
    int i = idx >> 7, d = idx & 127;
    const float* base = qkv + (size_t)(b * 25 + i) * 2048 + h * 128 + d;
    qs[i][d] = base[0];
    ks[i][d] = base[1024];
  }
  __syncthreads();
  const float scale = 0.08838834764831845f;
  for (int e = tid; e < 625; e += 256) {
    int i = e / 25, j = e % 25;
    float s = 0.f;
    for (int d = 0; d < 128; d++) s += qs[i][d] * ks[j][d];
    ps[i][j] = s * scale;
  }
  __syncthreads();
  if (tid < 25) {
    float mx = -1e30f;
    for (int j = 0; j < 25; j++) mx = fmaxf(mx, ps[tid][j]);
    float s = 0.f;
    for (int j = 0; j < 25; j++) { float ev = expf(ps[tid][j] - mx); ps[tid][j] = ev; s += ev; }
    float inv = 1.f / s;
    for (int j = 0; j < 25; j++) ps[tid][j] *= inv;
  }
  __syncthreads();
  float* out = sc + (size_t)(b * 8 + h) * 640;
  for (int e = tid; e < 625; e += 256) out[e] = ps[e / 25][e % 25];
}

// ---------------------------------------------------------------------------
// K5: generic per-row LayerNorm (fp32 src/dst).
// ---------------------------------------------------------------------------
template<int PER>
__global__ __launch_bounds__(256) void k_ln_rows(
    const float* __restrict__ src, float* __restrict__ dst,
    const float* __restrict__ g, const float* __restrict__ be,
    int dstStride, int dstOff)
{
  __shared__ float scratch[8];
  int row = blockIdx.x, tid = threadIdx.x;
  const int C = PER * 256;
  float v[PER];
  float s = 0.f, q = 0.f;
  #pragma unroll
  for (int p = 0; p < PER; p++) {
    v[p] = src[(size_t)row * C + p * 256 + tid];
    s += v[p]; q += v[p] * v[p];
  }
  block_reduce2(s, q, scratch);
  float mean = s / (float)C;
  float var = q / (float)C - mean * mean;
  float rs = rsqrtf(var + 1e-5f);
  #pragma unroll
  for (int p = 0; p < PER; p++) {
    int c = p * 256 + tid;
    dst[(size_t)row * dstStride + dstOff + c] = (v[p] - mean) * rs * g[c] + be[c];
  }
}

__global__ __launch_bounds__(256) void k_bcast_te(const float* __restrict__ te,
                                                  float* __restrict__ xcat)
{
  int row = blockIdx.x, tid = threadIdx.x;
  int n = row % 25;
  xcat[(size_t)row * 1280 + 512 + tid] = te[n * 512 + tid];
  xcat[(size_t)row * 1280 + 768 + tid] = te[n * 512 + 256 + tid];
}

// ---------------------------------------------------------------------------
// K6: adjacency build (single block)
// ---------------------------------------------------------------------------
__global__ __launch_bounds__(256) void k_adj(
    const float* __restrict__ sc, const float* __restrict__ te,
    const float* __restrict__ alpha_p, const float* __restrict__ dist,
    float* __restrict__ adj)
{
  __shared__ float als[625];
  __shared__ float ninv[25];
  __shared__ float scratch[8];
  __shared__ float mxs;
  int tid = threadIdx.x;

  for (int e = tid; e < 625; e += 256) {
    float s = 0.f;
    for (int gq = 0; gq < 256; gq++) s += sc[(size_t)gq * 640 + e];
    als[e] = s * (1.f / 256.f);
  }
  if (tid < 25) {
    float s = 0.f;
    const float* tp = te + tid * 512;
    for (int d = 0; d < 512; d++) s += tp[d] * tp[d];
    ninv[tid] = 1.f / fmaxf(sqrtf(s), 1e-8f);
  }
  __syncthreads();
  float alpha = alpha_p[0];
  for (int e = tid; e < 625; e += 256) {
    int i = e / 25, j = e % 25;
    float dt = 0.f;
    const float* ti = te + i * 512;
    const float* tj = te + j * 512;
    for (int d = 0; d < 512; d++) dt += ti[d] * tj[d];
    float emb = dt * ninv[i] * ninv[j];
    als[e] = (alpha * dist[e] + (1.f - alpha) * emb) * als[e];
  }
  __syncthreads();
  float lm = 0.f;
  for (int e = tid; e < 625; e += 256) {
    float a = fmaxf(als[e], 0.f);
    lm = fmaxf(lm, powf(a, 2.5f));
  }
  #pragma unroll
  for (int off = 32; off > 0; off >>= 1) lm = fmaxf(lm, __shfl_down(lm, off));
  int w = tid >> 6;
  if ((tid & 63) == 0) scratch[w] = lm;
  __syncthreads();
  if (tid == 0) {
    float m2 = scratch[0];
    for (int i = 1; i < 4; i++) m2 = fmaxf(m2, scratch[i]);
    mxs = m2;
  }
  __syncthreads();
  float mx = mxs;
  for (int e = tid; e < 625; e += 256) {
    float a = als[e];
    float m = powf(fmaxf(a, 0.f), 2.5f) / mx;
    adj[e] = (m >= 0.08f) ? a : 0.f;
  }
}

// ---------------------------------------------------------------------------
// K7: GCN adjacency mix
// ---------------------------------------------------------------------------
template<int RESID, int LNORM>
__global__ __launch_bounds__(256) void k_mix(
    const float* __restrict__ adj, const float* __restrict__ tmp,
    const float* __restrict__ bias, const float* __restrict__ resid,
    const float* __restrict__ g, const float* __restrict__ be,
    float* __restrict__ out)
{
  __shared__ float adjs[25];
  __shared__ float scratch[8];
  int row = blockIdx.x;
  int b = row / 25, i = row % 25;
  int f = threadIdx.x;
  if (f < 25) adjs[f] = adj[f * 25 + i];
  __syncthreads();
  float acc = bias[f];
  const float* tp = tmp + (size_t)b * 25 * 256 + f;
  #pragma unroll 5
  for (int j = 0; j < 25; j++) acc += adjs[j] * tp[(size_t)j * 256];
  if (RESID) acc += resid[(size_t)row * 256 + f];
  float v = acc;
  if (LNORM) {
    float s = v, q = v * v;
    block_reduce2(s, q, scratch);
    float mean = s * (1.f / 256.f);
    float var = q * (1.f / 256.f) - mean * mean;
    v = (v - mean) * rsqrtf(var + 1e-5f) * g[f] + be[f];
  }
  out[(size_t)row * 256 + f] = fmaxf(v, 0.f);
}

// ---------------------------------------------------------------------------
// launch
// ---------------------------------------------------------------------------
extern "C" void kernel_launch(void* const* d_in, const int* in_sizes, int n_in,
                              void* d_out, int out_size, void* d_ws, size_t ws_size,
                              hipStream_t stream)
{
  (void)in_sizes; (void)n_in; (void)out_size; (void)ws_size;

  const float* x         = (const float*)d_in[0];
  const float* seq1_w1   = (const float*)d_in[1];
  const float* seq1_b1   = (const float*)d_in[2];
  const float* seq1_w2   = (const float*)d_in[3];
  const float* seq1_b2   = (const float*)d_in[4];
  const float* ln2_g     = (const float*)d_in[5];
  const float* ln2_b     = (const float*)d_in[6];
  const float* gru_wih_f = (const float*)d_in[7];
  const float* gru_whh_f = (const float*)d_in[8];
  const float* gru_bih_f = (const float*)d_in[9];
  const float* gru_bhh_f = (const float*)d_in[10];
  const float* gru_wih_b = (const float*)d_in[11];
  const float* gru_whh_b = (const float*)d_in[12];
  const float* gru_bih_b = (const float*)d_in[13];
  const float* gru_bhh_b = (const float*)d_in[14];
  const float* ln_g      = (const float*)d_in[15];
  const float* ln_b      = (const float*)d_in[16];
  const float* attn_in_w = (const float*)d_in[17];
  const float* attn_in_b = (const float*)d_in[18];
  const float* fc_ta_w   = (const float*)d_in[19];
  const float* fc_ta_b   = (const float*)d_in[20];
  const float* ln3_g     = (const float*)d_in[21];
  const float* ln3_b     = (const float*)d_in[22];
  const float* sem_embs  = (const float*)d_in[23];
  const float* sem_w     = (const float*)d_in[24];
  const float* sem_b     = (const float*)d_in[25];
  const float* lnsem_g   = (const float*)d_in[26];
  const float* lnsem_b   = (const float*)d_in[27];
  const float* att_alpha = (const float*)d_in[28];
  const float* dist_adj  = (const float*)d_in[29];
  const float* gcn_w0    = (const float*)d_in[30];
  const float* gcn_b0    = (const float*)d_in[31];
  const float* gcn_w1    = (const float*)d_in[32];
  const float* gcn_b1    = (const float*)d_in[33];
  const float* gcn_w2    = (const float*)d_in[34];
  const float* gcn_b2    = (const float*)d_in[35];
  const float* gln1_g    = (const float*)d_in[36];
  const float* gln1_b    = (const float*)d_in[37];
  const float* gln2_g    = (const float*)d_in[38];
  const float* gln2_b    = (const float*)d_in[39];
  const float* enc_ln_g  = (const float*)d_in[40];
  const float* enc_ln_b  = (const float*)d_in[41];
  const float* fc_w      = (const float*)d_in[42];
  const float* fc_b      = (const float*)d_in[43];

  float* w = (float*)d_ws;
  ushort_t* hseqb = (ushort_t*)(w + O_HSEQB);
  ushort_t* wb    = (ushort_t*)(w + O_WB);
  float* hf32 = w + O_HF32;
  ushort_t* hbb = (ushort_t*)(w + O_HBB);
  float* hn   = w + O_HN;
  float* qkv  = w + O_QKV;
  float* sc   = w + O_SC;
  float* adjw = w + O_ADJ;
  float* wr   = w + O_WR;
  float* tep  = w + O_TEP;
  float* te   = w + O_TE;
  float* xcat = w + O_XCAT;
  float* gtmp = w + O_GTMP;
  float* xg0  = w + O_XG0;
  float* xg1  = w + O_XG1;
  float* xg2  = w + O_XG2;
  ushort_t* w1tb = (ushort_t*)(w + O_W1TB);
  ushort_t* w2tb = (ushort_t*)(w + O_W2TB);
  ushort_t* awb  = (ushort_t*)(w + O_AWB);
  ushort_t* ftwb = (ushort_t*)(w + O_FTWB);
  ushort_t* smwb = (ushort_t*)(w + O_SMWB);
  ushort_t* g0wb = (ushort_t*)(w + O_G0WB);
  ushort_t* g1wb = (ushort_t*)(w + O_G1WB);
  ushort_t* g2wb = (ushort_t*)(w + O_G2WB);
  ushort_t* fcwb = (ushort_t*)(w + O_FCWB);

  hipMemsetAsync(hf32, 0, (size_t)819200 * sizeof(float), stream);
  hipMemsetAsync(hbb, 0, (size_t)819200 * sizeof(ushort_t), stream);

  // ---- weight conversions ----
  k_cvt_w<<<3072, 256, 0, stream>>>(gru_wih_f, gru_whh_f, gru_wih_b, gru_whh_b, wb);
  k_cvt_t<<<dim3(8, 4), 256, 0, stream>>>(seq1_w1, w1tb, 100, 256, 128);
  k_cvt_t<<<dim3(16, 8), 256, 0, stream>>>(seq1_w2, w2tb, 256, 512, 256);
  k_cvt_plain<<<8192, 256, 0, stream>>>(attn_in_w, awb, 2048 * 1024);
  k_cvt_t<<<dim3(16, 32), 256, 0, stream>>>(fc_ta_w, ftwb, 1024, 512, 1024);
  k_cvt_t<<<dim3(16, 24), 256, 0, stream>>>(sem_w, smwb, 768, 512, 768);
  k_cvt_t<<<dim3(8, 32), 256, 0, stream>>>(gcn_w0, g0wb, 1024, 256, 1024);
  k_cvt_t<<<dim3(8, 8), 256, 0, stream>>>(gcn_w1, g1wb, 256, 256, 256);
  k_cvt_t<<<dim3(8, 8), 256, 0, stream>>>(gcn_w2, g2wb, 256, 256, 256);
  k_cvt_t<<<dim3(16, 40), 256, 0, stream>>>(fc_w, fcwb, 1280, 512, 1280);

  // ---- input MLP + LN (all-MFMA, fused) ----
  k_mlp_fused<<<750, 256, 0, stream>>>(x, w1tb, seq1_b1, w2tb, seq1_b2,
                                       ln2_g, ln2_b, hseqb);

  // ---- bidirectional GRU, 60 steps ----
  for (int t = 0; t < SS; t++) {
    k_gru_mfma<<<208, 256, 0, stream>>>(
        hseqb, wb, gru_bih_f, gru_bhh_f, gru_bih_b, gru_bhh_b, hf32, hbb, t);
  }

  // hn = LN(concat(hf, hb))
  k_ln_hn<<<800, 256, 0, stream>>>(hf32, hf32 + 409600, ln_g, ln_b, hn);

  // q,k projection
  k_bgemm<0><<<dim3(32, 13), 256, 0, stream>>>(
      hn, awb, attn_in_b, qkv, 800, 2048, 1024, 1024, 2048);

  // per (b,h) softmax attention
  k_scores<<<dim3(32, 8), 256, 0, stream>>>(qkv, sc);

  // semantic embedding projection + LN
  k_bgemm<0><<<dim3(8, 1), 256, 0, stream>>>(
      sem_embs, smwb, sem_b, tep, 25, 512, 768, 768, 512);
  k_ln_rows<2><<<25, 256, 0, stream>>>(tep, te, lnsem_g, lnsem_b, 512, 0);

  // fc_ta + LN3 -> Xcat[:, 0:512]
  k_bgemm<1><<<dim3(8, 13), 256, 0, stream>>>(
      hn, ftwb, fc_ta_b, wr, 800, 512, 1024, 1024, 512);
  k_ln_rows<2><<<800, 256, 0, stream>>>(wr, xcat, ln3_g, ln3_b, 1280, 0);
  k_bcast_te<<<800, 256, 0, stream>>>(te, xcat);

  // adjacency
  k_adj<<<1, 256, 0, stream>>>(sc, te, att_alpha, dist_adj, adjw);

  // GCN layer 0
  k_bgemm<0><<<dim3(4, 13), 256, 0, stream>>>(
      xcat, g0wb, nullptr, gtmp, 800, 256, 1024, 1280, 256);
  k_mix<0, 0><<<800, 256, 0, stream>>>(adjw, gtmp, gcn_b0, nullptr, nullptr, nullptr, xg0);
  // GCN layer 1
  k_bgemm<0><<<dim3(4, 13), 256, 0, stream>>>(
      xg0, g1wb, nullptr, gtmp, 800, 256, 256, 256, 256);
  k_mix<1, 1><<<800, 256, 0, stream>>>(adjw, gtmp, gcn_b1, xg0, gln1_g, gln1_b, xg1);
  // GCN layer 2
  k_bgemm<0><<<dim3(4, 13), 256, 0, stream>>>(
      xg1, g2wb, nullptr, gtmp, 800, 256, 256, 256, 256);
  k_mix<1, 1><<<800, 256, 0, stream>>>(adjw, gtmp, gcn_b2, xg1, gln2_g, gln2_b, xg2);

  // encoder LN -> Xcat[:, 1024:1280]
  k_ln_rows<1><<<800, 256, 0, stream>>>(xg2, xcat, enc_ln_g, enc_ln_b, 1280, 1024);

  // final fc + relu -> d_out
  k_bgemm<1><<<dim3(8, 13), 256, 0, stream>>>(
      xcat, fcwb, fc_b, (float*)d_out, 800, 512, 1280, 1280, 512);
}